// Round 12
// baseline (388.615 us; speedup 1.0000x reference)
//
#include <hip/hip_runtime.h>

typedef float f32x4 __attribute__((ext_vector_type(4)));
typedef float f32x16 __attribute__((ext_vector_type(16)));
typedef short s16x8 __attribute__((ext_vector_type(8)));
typedef unsigned int u32;

#define BSZ 4
#define SEQ 4096
#define DIM 256
#define NH 10
#define NG 4
#define CHK 1024
#define BS_TOT 16384   // BSZ*SEQ
#define HD 2560        // NH*DIM
#define LOG2E 1.44269504f

__device__ __forceinline__ unsigned short f2bf(float f) {
    unsigned int u = __builtin_bit_cast(unsigned int, f);
    u = (u + 0x7fffu + ((u >> 16) & 1u)) >> 16;
    return (unsigned short)u;
}

__device__ __forceinline__ void gload_lds16(const unsigned short* g, unsigned short* l) {
    __builtin_amdgcn_global_load_lds((const __attribute__((address_space(1))) u32*)g,
                                     (__attribute__((address_space(3))) u32*)l, 16, 0, 0);
}

__device__ __forceinline__ u32 cvtpk_bf16(float lo, float hi) {
    u32 r;
    asm("v_cvt_pk_bf16_f32 %0, %1, %2" : "=v"(r) : "v"(lo), "v"(hi));
    return r;
}

// Frag-major global layouts, per (b,g) chunk, per 32-key tile (8192 elems = 16KB):
//  KQv (QK A-frags):  off(key,d) = (d>>4)*512 + ((d>>3)&1)*256 + (key&31)*8 + (d&7)
//  KTv (PV B-frags):  off(key,d) = (d>>5)*1024 + (key>>4)*512 + ((key>>3)&1)*256 + (d&31)*8 + (key&7)
// Each chunk = contiguous 512 elems (1KB) = one wave's gload_lds16 / ds_read_b128 span.

// softmax half: p = exp2(st) (Q pre-scaled by log2e); accumulate l; pack+swap to PA frags
__device__ __forceinline__ void softmax_pack(const f32x16& st, float& l_part,
                                             s16x8& p0, s16x8& p1) {
    float e0 = __builtin_amdgcn_exp2f(st[0]),  e1 = __builtin_amdgcn_exp2f(st[1]);
    float e2 = __builtin_amdgcn_exp2f(st[2]),  e3 = __builtin_amdgcn_exp2f(st[3]);
    float e4 = __builtin_amdgcn_exp2f(st[4]),  e5 = __builtin_amdgcn_exp2f(st[5]);
    float e6 = __builtin_amdgcn_exp2f(st[6]),  e7 = __builtin_amdgcn_exp2f(st[7]);
    float e8 = __builtin_amdgcn_exp2f(st[8]),  e9 = __builtin_amdgcn_exp2f(st[9]);
    float eA = __builtin_amdgcn_exp2f(st[10]), eB = __builtin_amdgcn_exp2f(st[11]);
    float eC = __builtin_amdgcn_exp2f(st[12]), eD = __builtin_amdgcn_exp2f(st[13]);
    float eE = __builtin_amdgcn_exp2f(st[14]), eF = __builtin_amdgcn_exp2f(st[15]);
    l_part += (((e0 + e1) + (e2 + e3)) + ((e4 + e5) + (e6 + e7)))
            + (((e8 + e9) + (eA + eB)) + ((eC + eD) + (eE + eF)));
    u32 c0 = cvtpk_bf16(e0, e1), c1 = cvtpk_bf16(e2, e3);
    u32 c2 = cvtpk_bf16(e4, e5), c3 = cvtpk_bf16(e6, e7);
    u32 c4 = cvtpk_bf16(e8, e9), c5 = cvtpk_bf16(eA, eB);
    u32 c6 = cvtpk_bf16(eC, eD), c7 = cvtpk_bf16(eE, eF);
    asm("v_permlane32_swap_b32 %0, %1" : "+v"(c0), "+v"(c2));
    asm("v_permlane32_swap_b32 %0, %1" : "+v"(c1), "+v"(c3));
    asm("v_permlane32_swap_b32 %0, %1" : "+v"(c4), "+v"(c6));
    asm("v_permlane32_swap_b32 %0, %1" : "+v"(c5), "+v"(c7));
    struct { u32 a, b, c, d; } x0 = {c0, c1, c2, c3};
    struct { u32 a, b, c, d; } x1 = {c4, c5, c6, c7};
    p0 = __builtin_bit_cast(s16x8, x0);
    p1 = __builtin_bit_cast(s16x8, x1);
}

// ---------------- cast / transpose helpers ----------------

__global__ __launch_bounds__(256) void cast_f32_bf16(const float* __restrict__ s,
                                                     unsigned short* __restrict__ d, int n) {
    long i = 4L * (blockIdx.x * 256 + threadIdx.x);
    if (i < n) {
        float4 v = *(const float4*)(s + i);
        ushort4 o;
        o.x = f2bf(v.x); o.y = f2bf(v.y); o.z = f2bf(v.z); o.w = f2bf(v.w);
        *(ushort4*)(d + i) = o;
    }
}

// Wt[h][e][d] = W[h][d][e], fp32 -> bf16.  grid (8,8,2*NH), block 256
__global__ __launch_bounds__(256) void transpose_cast_w(const float* __restrict__ Wq,
                                                        const float* __restrict__ Wk,
                                                        unsigned short* __restrict__ wqt,
                                                        unsigned short* __restrict__ wkt) {
    const float* W = (blockIdx.z & 1) ? Wk : Wq;
    unsigned short* Wt = (blockIdx.z & 1) ? wkt : wqt;
    int h = blockIdx.z >> 1;
    __shared__ float tile[32][33];
    int d0 = blockIdx.x * 32, e0 = blockIdx.y * 32;
    int tx = threadIdx.x & 31, ty = threadIdx.x >> 5;
    const float* Wh = W + (long)h * 65536;
    unsigned short* Wth = Wt + (long)h * 65536;
#pragma unroll
    for (int r = ty; r < 32; r += 8) tile[r][tx] = Wh[(long)(d0 + r) * 256 + e0 + tx];
    __syncthreads();
#pragma unroll
    for (int r = ty; r < 32; r += 8) Wth[(long)(e0 + r) * 256 + d0 + tx] = f2bf(tile[tx][r]);
}

// ---------------- fallback small-tile GEMM (per-head path only) ----------------

__device__ __forceinline__ void gemm_body(const unsigned short* __restrict__ A, long lda,
                                          const unsigned short* __restrict__ Bt, long ldb,
                                          unsigned short* Cb, float* Cf, long ldc,
                                          int K, bool accum, long mbase,
                                          unsigned short* KQo, unsigned short* KTo,
                                          float cscale) {
    __shared__ unsigned short As[64 * 40];
    __shared__ unsigned short Bs[256 * 40];
    const int t = threadIdx.x;
    const int w = t >> 6, l = t & 63, lr = l & 15, lg = l >> 4;

    f32x4 acc[16];
#pragma unroll
    for (int i = 0; i < 16; i++) acc[i] = (f32x4){0.f, 0.f, 0.f, 0.f};

    const int ar = t >> 2, akc = (t & 3) * 8;

    for (int k0 = 0; k0 < K; k0 += 32) {
        *(s16x8*)(&As[ar * 40 + akc]) = *(const s16x8*)(A + (mbase + ar) * lda + k0 + akc);
#pragma unroll
        for (int s = 0; s < 4; s++) {
            int n = s * 64 + (t >> 2);
            *(s16x8*)(&Bs[n * 40 + akc]) = *(const s16x8*)(Bt + (long)n * ldb + k0 + akc);
        }
        __syncthreads();
        s16x8 af = *(const s16x8*)(&As[(w * 16 + lr) * 40 + lg * 8]);
        __builtin_amdgcn_s_setprio(1);
#pragma unroll
        for (int nt = 0; nt < 16; nt++) {
            s16x8 bf = *(const s16x8*)(&Bs[(nt * 16 + lr) * 40 + lg * 8]);
            acc[nt] = __builtin_amdgcn_mfma_f32_16x16x32_bf16(af, bf, acc[nt], 0, 0, 0);
        }
        __builtin_amdgcn_s_setprio(0);
        __syncthreads();
    }
    long m0 = mbase + w * 16 + lg * 4;
    if (Cb || Cf) {
#pragma unroll
        for (int nt = 0; nt < 16; nt++) {
            int col = nt * 16 + lr;
#pragma unroll
            for (int r = 0; r < 4; r++) {
                long idx = (m0 + r) * ldc + col;
                if (Cb) {
                    Cb[idx] = f2bf(acc[nt][r] * cscale);
                } else {
                    float v = acc[nt][r];
                    if (accum) v += Cf[idx];
                    Cf[idx] = v;
                }
            }
        }
    }
    if (KQo) {
        int bg = (int)(m0 >> 10);
        int kin = (int)(m0 & 1023);
        int kt = kin >> 5, kw = kin & 31;
        unsigned short* tb = KQo + (long)bg * (256 * 1024) + (long)kt * 8192;
#pragma unroll
        for (int nt = 0; nt < 16; nt++) {
            int d = nt * 16 + lr;
            unsigned short* p = tb + (d >> 4) * 512 + ((d >> 3) & 1) * 256 + (d & 7);
#pragma unroll
            for (int r = 0; r < 4; r++) p[(kw + r) * 8] = f2bf(acc[nt][r]);
        }
    }
    if (KTo) {
        int bg = (int)(m0 >> 10);
        int key0 = (int)(m0 & 1023);
        int kt = key0 >> 5, kw = key0 & 31;   // kw % 4 == 0
        unsigned short* base = KTo + (long)bg * (256 * 1024) + (long)kt * 8192
                             + (kw >> 4) * 512 + ((kw >> 3) & 1) * 256 + (kw & 7);
#pragma unroll
        for (int nt = 0; nt < 16; nt++) {
            int col = nt * 16 + lr;
            ushort4 v;
            v.x = f2bf(acc[nt][0]); v.y = f2bf(acc[nt][1]);
            v.z = f2bf(acc[nt][2]); v.w = f2bf(acc[nt][3]);
            *(ushort4*)(base + (col >> 5) * 1024 + (col & 31) * 8) = v;
        }
    }
}

__global__ __launch_bounds__(256) void proj_kernel(const unsigned short* __restrict__ xb,
                                                   const unsigned short* __restrict__ wqt,
                                                   const unsigned short* __restrict__ wkt,
                                                   unsigned short* Qb, unsigned short* KQb,
                                                   unsigned short* KTb,
                                                   int h0, long headStrideOut, long headStrideKT) {
    int h = h0 + blockIdx.y;
    bool isK = (blockIdx.z != 0);
    const unsigned short* Bt = (isK ? wkt : wqt) + (long)h * 65536;
    unsigned short* C = isK ? nullptr : (Qb + (long)blockIdx.y * headStrideOut);
    unsigned short* KQo = isK ? (KQb + (long)blockIdx.y * headStrideKT) : nullptr;
    unsigned short* KTo = isK ? (KTb + (long)blockIdx.y * headStrideKT) : nullptr;
    gemm_body(xb, 256, Bt, 256, C, nullptr, 256, 256, false, (long)blockIdx.x * 64,
              KQo, KTo, isK ? 1.0f : LOG2E);
}

__global__ __launch_bounds__(256) void final_kernel(const unsigned short* __restrict__ Ob, long lda,
                                                    const unsigned short* __restrict__ wob, long ldb,
                                                    float* out, int K, int accum) {
    gemm_body(Ob, lda, wob, ldb, nullptr, out, 256, K, accum != 0, (long)blockIdx.x * 64,
              nullptr, nullptr, 1.0f);
}

// ---------------- m97-style 128x128 GEMM: projections ----------------
// Q path: row-major C pre-scaled by log2e.  K path: KQv + KTv frag-major stores only.

__global__ __launch_bounds__(256, 3) void proj128(const unsigned short* __restrict__ xb,
                                                  const unsigned short* __restrict__ wqt,
                                                  const unsigned short* __restrict__ wkt,
                                                  unsigned short* __restrict__ Qb,
                                                  unsigned short* __restrict__ KQb,
                                                  unsigned short* __restrict__ KTb,
                                                  long headStrideOut, long headStrideKT) {
    __shared__ unsigned short As[2][128 * 32];
    __shared__ unsigned short Bs[2][128 * 32];

    const int lb = blockIdx.x;
    const int logical = (lb & 7) * 640 + (lb >> 3);
    const int x = logical / 40;
    const int u = logical - x * 40;
    const int mat = u >> 1, ntile = u & 1;
    const int h = mat >> 1;
    const bool isK = (mat & 1) != 0;

    const unsigned short* A = xb;
    const unsigned short* Bt = (isK ? wkt : wqt) + (long)h * 65536 + (long)ntile * 128 * 256;
    const long mbase = (long)x * 128;
    const int ncol0 = ntile * 128;

    const int t = threadIdx.x, w = t >> 6, l = t & 63, lr = l & 15, lg = l >> 4;
    const int wm = w >> 1, wn = w & 1;

    int sOff[2];
#pragma unroll
    for (int i = 0; i < 2; i++) {
        int row = w * 32 + i * 16 + (l >> 2);
        int cs2 = (l & 3) ^ (row & 3);
        sOff[i] = row * 256 + cs2 * 8;
    }

    f32x4 acc[4][4];
#pragma unroll
    for (int i = 0; i < 4; i++)
#pragma unroll
        for (int j = 0; j < 4; j++) acc[i][j] = (f32x4){0.f, 0.f, 0.f, 0.f};

#define PSTAGE(buf, k0) do {                                                     \
        _Pragma("unroll")                                                        \
        for (int i = 0; i < 2; i++)                                              \
            gload_lds16(A + mbase * 256 + (k0) + sOff[i],                        \
                        &As[buf][(w * 32 + i * 16) * 32]);                       \
        _Pragma("unroll")                                                        \
        for (int i = 0; i < 2; i++)                                              \
            gload_lds16(Bt + (k0) + sOff[i],                                     \
                        &Bs[buf][(w * 32 + i * 16) * 32]);                       \
    } while (0)

    PSTAGE(0, 0);
    __syncthreads();
    int cur = 0;
    for (int ks = 0; ks < 8; ++ks) {
        if (ks < 7) PSTAGE(cur ^ 1, (ks + 1) * 32);
        s16x8 a[4], b[4];
#pragma unroll
        for (int mf = 0; mf < 4; mf++) {
            int row = wm * 64 + mf * 16 + lr;
            a[mf] = *(const s16x8*)(&As[cur][row * 32 + (lg ^ (row & 3)) * 8]);
        }
#pragma unroll
        for (int nf = 0; nf < 4; nf++) {
            int row = wn * 64 + nf * 16 + lr;
            b[nf] = *(const s16x8*)(&Bs[cur][row * 32 + (lg ^ (row & 3)) * 8]);
        }
        __builtin_amdgcn_s_setprio(1);
#pragma unroll
        for (int mf = 0; mf < 4; mf++)
#pragma unroll
            for (int nf = 0; nf < 4; nf++)
                acc[mf][nf] = __builtin_amdgcn_mfma_f32_16x16x32_bf16(a[mf], b[nf], acc[mf][nf], 0, 0, 0);
        __builtin_amdgcn_s_setprio(0);
        __syncthreads();
        cur ^= 1;
    }
#undef PSTAGE

    long m0 = mbase + wm * 64 + lg * 4;
    if (!isK) {
        unsigned short* C = Qb + (long)h * headStrideOut;
#pragma unroll
        for (int mf = 0; mf < 4; mf++) {
            long mrow = m0 + mf * 16;
#pragma unroll
            for (int nf = 0; nf < 4; nf++) {
                int col = ncol0 + wn * 64 + nf * 16 + lr;
#pragma unroll
                for (int r = 0; r < 4; r++)
                    C[(mrow + r) * 256 + col] = f2bf(acc[mf][nf][r] * LOG2E);
            }
        }
    } else {
        unsigned short* KQo = KQb + (long)h * headStrideKT;
        unsigned short* KTo = KTb + (long)h * headStrideKT;
#pragma unroll
        for (int mf = 0; mf < 4; mf++) {
            long key = m0 + mf * 16;
            int bg = (int)(key >> 10), kin = (int)(key & 1023);
            int kt = kin >> 5, kw = kin & 31;
            unsigned short* qtb = KQo + (long)bg * (256 * 1024) + (long)kt * 8192;
            unsigned short* vtb = KTo + (long)bg * (256 * 1024) + (long)kt * 8192
                                + (kw >> 4) * 512 + ((kw >> 3) & 1) * 256 + (kw & 7);
#pragma unroll
            for (int nf = 0; nf < 4; nf++) {
                int d = ncol0 + wn * 64 + nf * 16 + lr;
                // KQv: scalar stores (keys kw..kw+3 at stride 8)
                unsigned short* p = qtb + (d >> 4) * 512 + ((d >> 3) & 1) * 256 + (d & 7);
#pragma unroll
                for (int r = 0; r < 4; r++) p[(kw + r) * 8] = f2bf(acc[mf][nf][r]);
                // KTv: vectorized (d contiguous in the d&31 dimension)
                ushort4 v;
                v.x = f2bf(acc[mf][nf][0]); v.y = f2bf(acc[mf][nf][1]);
                v.z = f2bf(acc[mf][nf][2]); v.w = f2bf(acc[mf][nf][3]);
                *(ushort4*)(vtb + (d >> 5) * 1024 + (d & 31) * 8) = v;
            }
        }
    }
}

// ---------------- m97-style 128x128 GEMM: final projection ----------------

__global__ __launch_bounds__(256, 3) void final128(const unsigned short* __restrict__ Ob,
                                                   long headStride,
                                                   const unsigned short* __restrict__ wob,
                                                   float* __restrict__ out) {
    __shared__ unsigned short As[2][128 * 32];
    __shared__ unsigned short Bs[2][128 * 32];

    const int lb = blockIdx.x;
    const int logical = (lb & 7) * 32 + (lb >> 3);
    const int x = logical >> 1, ntile = logical & 1;
    const long mbase = (long)x * 128;
    const int ncol0 = ntile * 128;
    const unsigned short* Bt = wob + (long)ncol0 * HD;

    const int t = threadIdx.x, w = t >> 6, l = t & 63, lr = l & 15, lg = l >> 4;
    const int wm = w >> 1, wn = w & 1;

    int sOffA[2], sOffB[2];
#pragma unroll
    for (int i = 0; i < 2; i++) {
        int row = w * 32 + i * 16 + (l >> 2);
        int cs2 = (l & 3) ^ (row & 3);
        sOffA[i] = row * 256 + cs2 * 8;
        sOffB[i] = row * HD + cs2 * 8;
    }

    f32x4 acc[4][4];
#pragma unroll
    for (int i = 0; i < 4; i++)
#pragma unroll
        for (int j = 0; j < 4; j++) acc[i][j] = (f32x4){0.f, 0.f, 0.f, 0.f};

#define FSTAGE(buf, k0) do {                                                     \
        const unsigned short* Asrc = Ob + (long)((k0) >> 8) * headStride         \
                                   + mbase * 256 + ((k0) & 255);                 \
        _Pragma("unroll")                                                        \
        for (int i = 0; i < 2; i++)                                              \
            gload_lds16(Asrc + sOffA[i], &As[buf][(w * 32 + i * 16) * 32]);      \
        _Pragma("unroll")                                                        \
        for (int i = 0; i < 2; i++)                                              \
            gload_lds16(Bt + (k0) + sOffB[i], &Bs[buf][(w * 32 + i * 16) * 32]); \
    } while (0)

    FSTAGE(0, 0);
    __syncthreads();
    int cur = 0;
    for (int ks = 0; ks < 80; ++ks) {
        if (ks < 79) FSTAGE(cur ^ 1, (ks + 1) * 32);
        s16x8 a[4], b[4];
#pragma unroll
        for (int mf = 0; mf < 4; mf++) {
            int row = wm * 64 + mf * 16 + lr;
            a[mf] = *(const s16x8*)(&As[cur][row * 32 + (lg ^ (row & 3)) * 8]);
        }
#pragma unroll
        for (int nf = 0; nf < 4; nf++) {
            int row = wn * 64 + nf * 16 + lr;
            b[nf] = *(const s16x8*)(&Bs[cur][row * 32 + (lg ^ (row & 3)) * 8]);
        }
        __builtin_amdgcn_s_setprio(1);
#pragma unroll
        for (int mf = 0; mf < 4; mf++)
#pragma unroll
            for (int nf = 0; nf < 4; nf++)
                acc[mf][nf] = __builtin_amdgcn_mfma_f32_16x16x32_bf16(a[mf], b[nf], acc[mf][nf], 0, 0, 0);
        __builtin_amdgcn_s_setprio(0);
        __syncthreads();
        cur ^= 1;
    }
#undef FSTAGE

    long m0 = mbase + wm * 64 + lg * 4;
#pragma unroll
    for (int mf = 0; mf < 4; mf++) {
        long mrow = m0 + mf * 16;
#pragma unroll
        for (int nf = 0; nf < 4; nf++) {
            int col = ncol0 + wn * 64 + nf * 16 + lr;
#pragma unroll
            for (int r = 0; r < 4; r++) out[(mrow + r) * 256 + col] = acc[mf][nf][r];
        }
    }
}

// ---------------- attention (32x32 MFMA, q=64/wave: 2 MFMAs per LDS read) -----
// 1D grid, block 256 (4 waves), q=64/wave (block = 256 q rows), 1 wave/SIMD
// (512-reg unified budget: 256 AGPR o + ~190 VGPR).
// XCD-chunked: logical = (lb&7)*chunkPerXcd + (lb>>3); -> bx(4) | by(16) | h.
// chunk g attends KV chunk (g+1)%4.  V == K.  Q pre-scaled by log2e -> p = exp2(S).
// Frag-major LDS (zero bank conflicts). Each kf/bv LDS read feeds TWO MFMAs
// (q-halves A/B) -> FLOP per LDS byte doubles vs q=32/wave (the round-10 limiter).

__global__ __launch_bounds__(256, 1) void attn_kernel(const unsigned short* __restrict__ Qb,
                                                      const unsigned short* __restrict__ KQg,
                                                      long headStrideQK,
                                                      const unsigned short* __restrict__ KTg,
                                                      long headStrideKT,
                                                      unsigned short* __restrict__ Ob,
                                                      long ldo, long colStride,
                                                      int chunkPerXcd) {
    const int lb = blockIdx.x;
    const int logical = (lb & 7) * chunkPerXcd + (lb >> 3);
    const int bx = logical & 3;
    const int by = (logical >> 2) & 15;
    const int h = logical >> 6;

    const unsigned short* Q = Qb + (long)h * colStride;  // Q row-major per-head
    const unsigned short* KQ = KQg + (long)h * headStrideQK;
    const unsigned short* KT = KTg + (long)h * headStrideKT;
    unsigned short* O = Ob + (long)h * colStride;
    const int b = by >> 2, g = by & 3;
    const long qrow0 = (long)b * SEQ + (long)g * CHK + (long)bx * 256;
    const int bgk = b * NG + ((g + 1) & 3);
    const unsigned short* KQc = KQ + (long)bgk * (256 * 1024);
    const unsigned short* KTc = KT + (long)bgk * (256 * 1024);

    __shared__ unsigned short Klds[2][8192];  // 2 x 16KB, frag-major
    __shared__ unsigned short Vlds[2][8192];  // 2 x 16KB, frag-major

    const int t = threadIdx.x;
    const int w = t >> 6, l = t & 63, l31 = l & 31, hi = l >> 5;

    // Q fragments for both q-halves: lane holds Q[q][d = s*16 + hi*8 + j]
    s16x8 qfA[16], qfB[16];
    {
        const unsigned short* qpA = Q + (qrow0 + w * 64 + l31) * 256 + hi * 8;
        const unsigned short* qpB = qpA + 32 * 256;
#pragma unroll
        for (int s = 0; s < 16; s++) {
            qfA[s] = *(const s16x8*)(qpA + s * 16);
            qfB[s] = *(const s16x8*)(qpB + s * 16);
        }
    }

    f32x16 oA[8], oB[8];
#pragma unroll
    for (int i = 0; i < 8; i++)
#pragma unroll
        for (int j = 0; j < 16; j++) { oA[i][j] = 0.f; oB[i][j] = 0.f; }
    float lpA = 0.f, lpB = 0.f;

#define STAGE(buf, kt_) do {                                                    \
        const unsigned short* Ks = KQc + (long)(kt_) * 8192 + l * 8;            \
        const unsigned short* Vs = KTc + (long)(kt_) * 8192 + l * 8;            \
        _Pragma("unroll")                                                       \
        for (int i = 0; i < 4; i++) {                                           \
            int c = w * 4 + i;                                                  \
            gload_lds16(Ks + c * 512, &Klds[buf][c * 512]);                     \
            gload_lds16(Vs + c * 512, &Vlds[buf][c * 512]);                     \
        }                                                                       \
    } while (0)

    STAGE(0, 0);
    __syncthreads();
    int cur = 0;

    for (int kt = 0; kt < 32; ++kt) {
        if (kt < 31) STAGE(cur ^ 1, kt + 1);   // prefetch next tile under compute

        // S = K_tile @ Q^T for both q-halves; each kf read feeds 2 MFMAs
        f32x16 stA, stB;
#pragma unroll
        for (int j = 0; j < 16; j++) { stA[j] = 0.f; stB[j] = 0.f; }
        __builtin_amdgcn_s_setprio(1);
#pragma unroll
        for (int ks = 0; ks < 16; ks++) {
            s16x8 kf = *(const s16x8*)(&Klds[cur][ks * 512 + l * 8]);
            stA = __builtin_amdgcn_mfma_f32_32x32x16_bf16(kf, qfA[ks], stA, 0, 0, 0);
            stB = __builtin_amdgcn_mfma_f32_32x32x16_bf16(kf, qfB[ks], stB, 0, 0, 0);
        }
        __builtin_amdgcn_s_setprio(0);

        // softmax both halves -> PA frags
        s16x8 paA0, paA1, paB0, paB1;
        softmax_pack(stA, lpA, paA0, paA1);
        softmax_pack(stB, lpB, paB0, paB1);

        // O += P @ V; each bv read feeds 2 MFMAs
        __builtin_amdgcn_s_setprio(1);
#pragma unroll
        for (int ks = 0; ks < 2; ks++) {
            s16x8 pA = ks ? paA1 : paA0;
            s16x8 pB = ks ? paB1 : paB0;
#pragma unroll
            for (int nt = 0; nt < 8; nt++) {
                s16x8 bv = *(const s16x8*)(&Vlds[cur][(nt * 2 + ks) * 512 + l * 8]);
                oA[nt] = __builtin_amdgcn_mfma_f32_32x32x16_bf16(pA, bv, oA[nt], 0, 0, 0);
                oB[nt] = __builtin_amdgcn_mfma_f32_32x32x16_bf16(pB, bv, oB[nt], 0, 0, 0);
            }
        }
        __builtin_amdgcn_s_setprio(0);

        __syncthreads();   // drains vmcnt(0): next tile staged; cur reusable
        cur ^= 1;
    }
#undef STAGE

    // epilogue: per half, reduce l across partner lane-half, scale + store
#pragma unroll
    for (int half = 0; half < 2; half++) {
        float lp = half ? lpB : lpA;
        float lt = lp + __shfl_xor(lp, 32);
        float rinv = 1.0f / lt;
        float ri[16];
#pragma unroll
        for (int reg = 0; reg < 16; reg++) {
            int qr = (reg & 3) + 8 * (reg >> 2) + 4 * hi;
            ri[reg] = __shfl(rinv, qr);
        }
        long orow0 = qrow0 + w * 64 + half * 32;
#pragma unroll
        for (int nt = 0; nt < 8; nt++) {
#pragma unroll
            for (int reg = 0; reg < 16; reg++) {
                int qr = (reg & 3) + 8 * (reg >> 2) + 4 * hi;
                float v = half ? oB[nt][reg] : oA[nt][reg];
                O[(orow0 + qr) * ldo + nt * 32 + l31] = f2bf(v * ri[reg]);
            }
        }
    }
}

// ---------------- host ----------------

extern "C" void kernel_launch(void* const* d_in, const int* in_sizes, int n_in,
                              void* d_out, int out_size, void* d_ws, size_t ws_size,
                              hipStream_t stream) {
    const float* x  = (const float*)d_in[0];
    const float* Wq = (const float*)d_in[1];
    const float* Wk = (const float*)d_in[2];
    const float* Wo = (const float*)d_in[3];
    float* out = (float*)d_out;
    char* ws = (char*)d_ws;

    unsigned short* xb  = (unsigned short*)(ws);
    unsigned short* wqt = (unsigned short*)(ws + 8388608);
    unsigned short* wkt = (unsigned short*)(ws + 9699328);
    unsigned short* wob = (unsigned short*)(ws + 11010048);
    char* dyn = ws + 12320768;

    cast_f32_bf16<<<4096, 256, 0, stream>>>(x, xb, BS_TOT * DIM);
    cast_f32_bf16<<<640, 256, 0, stream>>>(Wo, wob, DIM * HD);
    transpose_cast_w<<<dim3(8, 8, 2 * NH), 256, 0, stream>>>(Wq, Wk, wqt, wkt);

    const long perHeadElems = (long)BS_TOT * DIM;                // 4,194,304 (8MB bf16)
    const size_t FULL_NEED = 12320768ULL + 3ULL * 83886080ULL;   // ~264 MB (proven fits)

    if (ws_size >= FULL_NEED) {
        unsigned short* Qb  = (unsigned short*)dyn;              // also O (aliased)
        unsigned short* KQb = Qb + (long)NH * perHeadElems;
        unsigned short* KTb = KQb + (long)NH * perHeadElems;
        proj128<<<5120, 256, 0, stream>>>(xb, wqt, wkt, Qb, KQb, KTb,
                                          perHeadElems, perHeadElems);
        // q=64/wave: 640 blocks (4 q-tiles x 16 bg x 10 heads), XCD chunk 80
        attn_kernel<<<640, 256, 0, stream>>>(Qb, KQb, perHeadElems, KTb, perHeadElems,
                                             Qb, 256, perHeadElems, 80);
        final128<<<256, 256, 0, stream>>>(Qb, perHeadElems, wob, out);
    } else {
        unsigned short* Qh  = (unsigned short*)dyn;              // also O (aliased)
        unsigned short* KQh = Qh + perHeadElems;
        unsigned short* KTh = KQh + perHeadElems;
        hipMemsetAsync(d_out, 0, (size_t)out_size * 4, stream);
        for (int h = 0; h < NH; ++h) {
            proj_kernel<<<dim3(256, 1, 2), 256, 0, stream>>>(xb, wqt, wkt, Qh, KQh, KTh, h, 0, 0);
            attn_kernel<<<64, 256, 0, stream>>>(Qh, KQh, 0, KTh, 0, Qh, 256, 0, 8);
            final_kernel<<<256, 256, 0, stream>>>(Qh, 256, wob + h * 256, HD, out, 256, 1);
        }
    }
}

// Round 13
// 349.845 us; speedup vs baseline: 1.1108x; 1.1108x over previous
//
#include <hip/hip_runtime.h>

typedef float f32x4 __attribute__((ext_vector_type(4)));
typedef float f32x16 __attribute__((ext_vector_type(16)));
typedef short s16x8 __attribute__((ext_vector_type(8)));
typedef unsigned int u32;

#define BSZ 4
#define SEQ 4096
#define DIM 256
#define NH 10
#define NG 4
#define CHK 1024
#define BS_TOT 16384   // BSZ*SEQ
#define HD 2560        // NH*DIM
#define LOG2E 1.44269504f

__device__ __forceinline__ unsigned short f2bf(float f) {
    unsigned int u = __builtin_bit_cast(unsigned int, f);
    u = (u + 0x7fffu + ((u >> 16) & 1u)) >> 16;
    return (unsigned short)u;
}

__device__ __forceinline__ void gload_lds16(const unsigned short* g, unsigned short* l) {
    __builtin_amdgcn_global_load_lds((const __attribute__((address_space(1))) u32*)g,
                                     (__attribute__((address_space(3))) u32*)l, 16, 0, 0);
}

__device__ __forceinline__ u32 cvtpk_bf16(float lo, float hi) {
    u32 r;
    asm("v_cvt_pk_bf16_f32 %0, %1, %2" : "=v"(r) : "v"(lo), "v"(hi));
    return r;
}

// Frag-major global layouts, per (b,g) chunk, per 32-key tile (8192 elems = 16KB):
//  KQv (QK A-frags):  off(key,d) = (d>>4)*512 + ((d>>3)&1)*256 + (key&31)*8 + (d&7)
//  KTv (PV B-frags):  off(key,d) = (d>>5)*1024 + (key>>4)*512 + ((key>>3)&1)*256 + (d&31)*8 + (key&7)
// Each chunk = contiguous 512 elems (1KB) = one wave's gload_lds16 / ds_read_b128 span.

// ---------------- cast / transpose helpers ----------------

__global__ __launch_bounds__(256) void cast_f32_bf16(const float* __restrict__ s,
                                                     unsigned short* __restrict__ d, int n) {
    long i = 4L * (blockIdx.x * 256 + threadIdx.x);
    if (i < n) {
        float4 v = *(const float4*)(s + i);
        ushort4 o;
        o.x = f2bf(v.x); o.y = f2bf(v.y); o.z = f2bf(v.z); o.w = f2bf(v.w);
        *(ushort4*)(d + i) = o;
    }
}

// Wt[h][e][d] = W[h][d][e], fp32 -> bf16.  grid (8,8,2*NH), block 256
__global__ __launch_bounds__(256) void transpose_cast_w(const float* __restrict__ Wq,
                                                        const float* __restrict__ Wk,
                                                        unsigned short* __restrict__ wqt,
                                                        unsigned short* __restrict__ wkt) {
    const float* W = (blockIdx.z & 1) ? Wk : Wq;
    unsigned short* Wt = (blockIdx.z & 1) ? wkt : wqt;
    int h = blockIdx.z >> 1;
    __shared__ float tile[32][33];
    int d0 = blockIdx.x * 32, e0 = blockIdx.y * 32;
    int tx = threadIdx.x & 31, ty = threadIdx.x >> 5;
    const float* Wh = W + (long)h * 65536;
    unsigned short* Wth = Wt + (long)h * 65536;
#pragma unroll
    for (int r = ty; r < 32; r += 8) tile[r][tx] = Wh[(long)(d0 + r) * 256 + e0 + tx];
    __syncthreads();
#pragma unroll
    for (int r = ty; r < 32; r += 8) Wth[(long)(e0 + r) * 256 + d0 + tx] = f2bf(tile[tx][r]);
}

// ---------------- fallback small-tile GEMM (per-head path only) ----------------

__device__ __forceinline__ void gemm_body(const unsigned short* __restrict__ A, long lda,
                                          const unsigned short* __restrict__ Bt, long ldb,
                                          unsigned short* Cb, float* Cf, long ldc,
                                          int K, bool accum, long mbase,
                                          unsigned short* KQo, unsigned short* KTo,
                                          float cscale) {
    __shared__ unsigned short As[64 * 40];
    __shared__ unsigned short Bs[256 * 40];
    const int t = threadIdx.x;
    const int w = t >> 6, l = t & 63, lr = l & 15, lg = l >> 4;

    f32x4 acc[16];
#pragma unroll
    for (int i = 0; i < 16; i++) acc[i] = (f32x4){0.f, 0.f, 0.f, 0.f};

    const int ar = t >> 2, akc = (t & 3) * 8;

    for (int k0 = 0; k0 < K; k0 += 32) {
        *(s16x8*)(&As[ar * 40 + akc]) = *(const s16x8*)(A + (mbase + ar) * lda + k0 + akc);
#pragma unroll
        for (int s = 0; s < 4; s++) {
            int n = s * 64 + (t >> 2);
            *(s16x8*)(&Bs[n * 40 + akc]) = *(const s16x8*)(Bt + (long)n * ldb + k0 + akc);
        }
        __syncthreads();
        s16x8 af = *(const s16x8*)(&As[(w * 16 + lr) * 40 + lg * 8]);
        __builtin_amdgcn_s_setprio(1);
#pragma unroll
        for (int nt = 0; nt < 16; nt++) {
            s16x8 bf = *(const s16x8*)(&Bs[(nt * 16 + lr) * 40 + lg * 8]);
            acc[nt] = __builtin_amdgcn_mfma_f32_16x16x32_bf16(af, bf, acc[nt], 0, 0, 0);
        }
        __builtin_amdgcn_s_setprio(0);
        __syncthreads();
    }
    long m0 = mbase + w * 16 + lg * 4;
    if (Cb || Cf) {
#pragma unroll
        for (int nt = 0; nt < 16; nt++) {
            int col = nt * 16 + lr;
#pragma unroll
            for (int r = 0; r < 4; r++) {
                long idx = (m0 + r) * ldc + col;
                if (Cb) {
                    Cb[idx] = f2bf(acc[nt][r] * cscale);
                } else {
                    float v = acc[nt][r];
                    if (accum) v += Cf[idx];
                    Cf[idx] = v;
                }
            }
        }
    }
    if (KQo) {
        int bg = (int)(m0 >> 10);
        int kin = (int)(m0 & 1023);
        int kt = kin >> 5, kw = kin & 31;
        unsigned short* tb = KQo + (long)bg * (256 * 1024) + (long)kt * 8192;
#pragma unroll
        for (int nt = 0; nt < 16; nt++) {
            int d = nt * 16 + lr;
            unsigned short* p = tb + (d >> 4) * 512 + ((d >> 3) & 1) * 256 + (d & 7);
#pragma unroll
            for (int r = 0; r < 4; r++) p[(kw + r) * 8] = f2bf(acc[nt][r]);
        }
    }
    if (KTo) {
        int bg = (int)(m0 >> 10);
        int key0 = (int)(m0 & 1023);
        int kt = key0 >> 5, kw = key0 & 31;   // kw % 4 == 0
        unsigned short* base = KTo + (long)bg * (256 * 1024) + (long)kt * 8192
                             + (kw >> 4) * 512 + ((kw >> 3) & 1) * 256 + (kw & 7);
#pragma unroll
        for (int nt = 0; nt < 16; nt++) {
            int col = nt * 16 + lr;
            ushort4 v;
            v.x = f2bf(acc[nt][0]); v.y = f2bf(acc[nt][1]);
            v.z = f2bf(acc[nt][2]); v.w = f2bf(acc[nt][3]);
            *(ushort4*)(base + (col >> 5) * 1024 + (col & 31) * 8) = v;
        }
    }
}

__global__ __launch_bounds__(256) void proj_kernel(const unsigned short* __restrict__ xb,
                                                   const unsigned short* __restrict__ wqt,
                                                   const unsigned short* __restrict__ wkt,
                                                   unsigned short* Qb, unsigned short* KQb,
                                                   unsigned short* KTb,
                                                   int h0, long headStrideOut, long headStrideKT) {
    int h = h0 + blockIdx.y;
    bool isK = (blockIdx.z != 0);
    const unsigned short* Bt = (isK ? wkt : wqt) + (long)h * 65536;
    unsigned short* C = isK ? nullptr : (Qb + (long)blockIdx.y * headStrideOut);
    unsigned short* KQo = isK ? (KQb + (long)blockIdx.y * headStrideKT) : nullptr;
    unsigned short* KTo = isK ? (KTb + (long)blockIdx.y * headStrideKT) : nullptr;
    gemm_body(xb, 256, Bt, 256, C, nullptr, 256, 256, false, (long)blockIdx.x * 64,
              KQo, KTo, isK ? 1.0f : LOG2E);
}

__global__ __launch_bounds__(256) void final_kernel(const unsigned short* __restrict__ Ob, long lda,
                                                    const unsigned short* __restrict__ wob, long ldb,
                                                    float* out, int K, int accum) {
    gemm_body(Ob, lda, wob, ldb, nullptr, out, 256, K, accum != 0, (long)blockIdx.x * 64,
              nullptr, nullptr, 1.0f);
}

// ---------------- m97-style 128x128 GEMM: projections ----------------
// Q path: row-major C pre-scaled by log2e.  K path: KQv + KTv frag-major stores only.

__global__ __launch_bounds__(256, 3) void proj128(const unsigned short* __restrict__ xb,
                                                  const unsigned short* __restrict__ wqt,
                                                  const unsigned short* __restrict__ wkt,
                                                  unsigned short* __restrict__ Qb,
                                                  unsigned short* __restrict__ KQb,
                                                  unsigned short* __restrict__ KTb,
                                                  long headStrideOut, long headStrideKT) {
    __shared__ unsigned short As[2][128 * 32];
    __shared__ unsigned short Bs[2][128 * 32];

    const int lb = blockIdx.x;
    const int logical = (lb & 7) * 640 + (lb >> 3);
    const int x = logical / 40;
    const int u = logical - x * 40;
    const int mat = u >> 1, ntile = u & 1;
    const int h = mat >> 1;
    const bool isK = (mat & 1) != 0;

    const unsigned short* A = xb;
    const unsigned short* Bt = (isK ? wkt : wqt) + (long)h * 65536 + (long)ntile * 128 * 256;
    const long mbase = (long)x * 128;
    const int ncol0 = ntile * 128;

    const int t = threadIdx.x, w = t >> 6, l = t & 63, lr = l & 15, lg = l >> 4;
    const int wm = w >> 1, wn = w & 1;

    int sOff[2];
#pragma unroll
    for (int i = 0; i < 2; i++) {
        int row = w * 32 + i * 16 + (l >> 2);
        int cs2 = (l & 3) ^ (row & 3);
        sOff[i] = row * 256 + cs2 * 8;
    }

    f32x4 acc[4][4];
#pragma unroll
    for (int i = 0; i < 4; i++)
#pragma unroll
        for (int j = 0; j < 4; j++) acc[i][j] = (f32x4){0.f, 0.f, 0.f, 0.f};

#define PSTAGE(buf, k0) do {                                                     \
        _Pragma("unroll")                                                        \
        for (int i = 0; i < 2; i++)                                              \
            gload_lds16(A + mbase * 256 + (k0) + sOff[i],                        \
                        &As[buf][(w * 32 + i * 16) * 32]);                       \
        _Pragma("unroll")                                                        \
        for (int i = 0; i < 2; i++)                                              \
            gload_lds16(Bt + (k0) + sOff[i],                                     \
                        &Bs[buf][(w * 32 + i * 16) * 32]);                       \
    } while (0)

    PSTAGE(0, 0);
    __syncthreads();
    int cur = 0;
    for (int ks = 0; ks < 8; ++ks) {
        if (ks < 7) PSTAGE(cur ^ 1, (ks + 1) * 32);
        s16x8 a[4], b[4];
#pragma unroll
        for (int mf = 0; mf < 4; mf++) {
            int row = wm * 64 + mf * 16 + lr;
            a[mf] = *(const s16x8*)(&As[cur][row * 32 + (lg ^ (row & 3)) * 8]);
        }
#pragma unroll
        for (int nf = 0; nf < 4; nf++) {
            int row = wn * 64 + nf * 16 + lr;
            b[nf] = *(const s16x8*)(&Bs[cur][row * 32 + (lg ^ (row & 3)) * 8]);
        }
        __builtin_amdgcn_s_setprio(1);
#pragma unroll
        for (int mf = 0; mf < 4; mf++)
#pragma unroll
            for (int nf = 0; nf < 4; nf++)
                acc[mf][nf] = __builtin_amdgcn_mfma_f32_16x16x32_bf16(a[mf], b[nf], acc[mf][nf], 0, 0, 0);
        __builtin_amdgcn_s_setprio(0);
        __syncthreads();
        cur ^= 1;
    }
#undef PSTAGE

    long m0 = mbase + wm * 64 + lg * 4;
    if (!isK) {
        unsigned short* C = Qb + (long)h * headStrideOut;
#pragma unroll
        for (int mf = 0; mf < 4; mf++) {
            long mrow = m0 + mf * 16;
#pragma unroll
            for (int nf = 0; nf < 4; nf++) {
                int col = ncol0 + wn * 64 + nf * 16 + lr;
#pragma unroll
                for (int r = 0; r < 4; r++)
                    C[(mrow + r) * 256 + col] = f2bf(acc[mf][nf][r] * LOG2E);
            }
        }
    } else {
        unsigned short* KQo = KQb + (long)h * headStrideKT;
        unsigned short* KTo = KTb + (long)h * headStrideKT;
#pragma unroll
        for (int mf = 0; mf < 4; mf++) {
            long key = m0 + mf * 16;
            int bg = (int)(key >> 10), kin = (int)(key & 1023);
            int kt = kin >> 5, kw = kin & 31;
            unsigned short* qtb = KQo + (long)bg * (256 * 1024) + (long)kt * 8192;
            unsigned short* vtb = KTo + (long)bg * (256 * 1024) + (long)kt * 8192
                                + (kw >> 4) * 512 + ((kw >> 3) & 1) * 256 + (kw & 7);
#pragma unroll
            for (int nf = 0; nf < 4; nf++) {
                int d = ncol0 + wn * 64 + nf * 16 + lr;
                // KQv: scalar stores (keys kw..kw+3 at stride 8)
                unsigned short* p = qtb + (d >> 4) * 512 + ((d >> 3) & 1) * 256 + (d & 7);
#pragma unroll
                for (int r = 0; r < 4; r++) p[(kw + r) * 8] = f2bf(acc[mf][nf][r]);
                // KTv: vectorized (d contiguous in the d&31 dimension)
                ushort4 v;
                v.x = f2bf(acc[mf][nf][0]); v.y = f2bf(acc[mf][nf][1]);
                v.z = f2bf(acc[mf][nf][2]); v.w = f2bf(acc[mf][nf][3]);
                *(ushort4*)(vtb + (d >> 5) * 1024 + (d & 31) * 8) = v;
            }
        }
    }
}

// ---------------- m97-style 128x128 GEMM: final projection ----------------

__global__ __launch_bounds__(256, 3) void final128(const unsigned short* __restrict__ Ob,
                                                   long headStride,
                                                   const unsigned short* __restrict__ wob,
                                                   float* __restrict__ out) {
    __shared__ unsigned short As[2][128 * 32];
    __shared__ unsigned short Bs[2][128 * 32];

    const int lb = blockIdx.x;
    const int logical = (lb & 7) * 32 + (lb >> 3);
    const int x = logical >> 1, ntile = logical & 1;
    const long mbase = (long)x * 128;
    const int ncol0 = ntile * 128;
    const unsigned short* Bt = wob + (long)ncol0 * HD;

    const int t = threadIdx.x, w = t >> 6, l = t & 63, lr = l & 15, lg = l >> 4;
    const int wm = w >> 1, wn = w & 1;

    int sOffA[2], sOffB[2];
#pragma unroll
    for (int i = 0; i < 2; i++) {
        int row = w * 32 + i * 16 + (l >> 2);
        int cs2 = (l & 3) ^ (row & 3);
        sOffA[i] = row * 256 + cs2 * 8;
        sOffB[i] = row * HD + cs2 * 8;
    }

    f32x4 acc[4][4];
#pragma unroll
    for (int i = 0; i < 4; i++)
#pragma unroll
        for (int j = 0; j < 4; j++) acc[i][j] = (f32x4){0.f, 0.f, 0.f, 0.f};

#define FSTAGE(buf, k0) do {                                                     \
        const unsigned short* Asrc = Ob + (long)((k0) >> 8) * headStride         \
                                   + mbase * 256 + ((k0) & 255);                 \
        _Pragma("unroll")                                                        \
        for (int i = 0; i < 2; i++)                                              \
            gload_lds16(Asrc + sOffA[i], &As[buf][(w * 32 + i * 16) * 32]);      \
        _Pragma("unroll")                                                        \
        for (int i = 0; i < 2; i++)                                              \
            gload_lds16(Bt + (k0) + sOffB[i], &Bs[buf][(w * 32 + i * 16) * 32]); \
    } while (0)

    FSTAGE(0, 0);
    __syncthreads();
    int cur = 0;
    for (int ks = 0; ks < 80; ++ks) {
        if (ks < 79) FSTAGE(cur ^ 1, (ks + 1) * 32);
        s16x8 a[4], b[4];
#pragma unroll
        for (int mf = 0; mf < 4; mf++) {
            int row = wm * 64 + mf * 16 + lr;
            a[mf] = *(const s16x8*)(&As[cur][row * 32 + (lg ^ (row & 3)) * 8]);
        }
#pragma unroll
        for (int nf = 0; nf < 4; nf++) {
            int row = wn * 64 + nf * 16 + lr;
            b[nf] = *(const s16x8*)(&Bs[cur][row * 32 + (lg ^ (row & 3)) * 8]);
        }
        __builtin_amdgcn_s_setprio(1);
#pragma unroll
        for (int mf = 0; mf < 4; mf++)
#pragma unroll
            for (int nf = 0; nf < 4; nf++)
                acc[mf][nf] = __builtin_amdgcn_mfma_f32_16x16x32_bf16(a[mf], b[nf], acc[mf][nf], 0, 0, 0);
        __builtin_amdgcn_s_setprio(0);
        __syncthreads();
        cur ^= 1;
    }
#undef FSTAGE

    long m0 = mbase + wm * 64 + lg * 4;
#pragma unroll
    for (int mf = 0; mf < 4; mf++) {
        long mrow = m0 + mf * 16;
#pragma unroll
        for (int nf = 0; nf < 4; nf++) {
            int col = ncol0 + wn * 64 + nf * 16 + lr;
#pragma unroll
            for (int r = 0; r < 4; r++) out[(mrow + r) * 256 + col] = acc[mf][nf][r];
        }
    }
}

// ---------------- attention (32x32 MFMA, frag-major LDS, dual QK chains) ------
// Round-10 structure (best measured: 197us attn) + ONE change: QK split into two
// interleaved accumulator chains (stA: d-chunks 0-7, stB: 8-15) so each MFMA's
// dependent-latency gap is filled by the other chain; st = stA + stB.
// 1D grid 1280, block 256 (4 waves), q=32/wave, ~2 waves/SIMD.
// XCD-chunked: logical = (lb&7)*160 + (lb>>3); -> bx(8) | by(16) | h.
// chunk g attends KV chunk (g+1)%4.  V == K.  Q pre-scaled by log2e -> p = exp2(S).

__global__ __launch_bounds__(256, 2) void attn_kernel(const unsigned short* __restrict__ Qb,
                                                      const unsigned short* __restrict__ KQg,
                                                      long headStrideQK,
                                                      const unsigned short* __restrict__ KTg,
                                                      long headStrideKT,
                                                      unsigned short* __restrict__ Ob,
                                                      long ldo, long colStride,
                                                      int chunkPerXcd) {
    const int lb = blockIdx.x;
    const int logical = (lb & 7) * chunkPerXcd + (lb >> 3);
    const int bx = logical & 7;
    const int by = (logical >> 3) & 15;
    const int h = logical >> 7;

    const unsigned short* Q = Qb + (long)h * colStride;  // Q row-major per-head
    const unsigned short* KQ = KQg + (long)h * headStrideQK;
    const unsigned short* KT = KTg + (long)h * headStrideKT;
    unsigned short* O = Ob + (long)h * colStride;
    const int b = by >> 2, g = by & 3;
    const long qrow0 = (long)b * SEQ + (long)g * CHK + (long)bx * 128;
    const int bgk = b * NG + ((g + 1) & 3);
    const unsigned short* KQc = KQ + (long)bgk * (256 * 1024);
    const unsigned short* KTc = KT + (long)bgk * (256 * 1024);

    __shared__ unsigned short Klds[2][8192];  // 2 x 16KB, frag-major
    __shared__ unsigned short Vlds[2][8192];  // 2 x 16KB, frag-major

    const int t = threadIdx.x;
    const int w = t >> 6, l = t & 63, l31 = l & 31, hi = l >> 5;

    // Q fragments (B-operand, 32x32x16): lane holds Q[q = l31][d = s*16 + hi*8 + j]
    s16x8 qf[16];
    {
        const unsigned short* qp = Q + (qrow0 + w * 32 + l31) * 256 + hi * 8;
#pragma unroll
        for (int s = 0; s < 16; s++) qf[s] = *(const s16x8*)(qp + s * 16);
    }

    f32x16 o[8];
#pragma unroll
    for (int i = 0; i < 8; i++)
#pragma unroll
        for (int j = 0; j < 16; j++) o[i][j] = 0.f;
    float l_part = 0.f;

#define STAGE(buf, kt_) do {                                                    \
        const unsigned short* Ks = KQc + (long)(kt_) * 8192 + l * 8;            \
        const unsigned short* Vs = KTc + (long)(kt_) * 8192 + l * 8;            \
        _Pragma("unroll")                                                       \
        for (int i = 0; i < 4; i++) {                                           \
            int c = w * 4 + i;                                                  \
            gload_lds16(Ks + c * 512, &Klds[buf][c * 512]);                     \
            gload_lds16(Vs + c * 512, &Vlds[buf][c * 512]);                     \
        }                                                                       \
    } while (0)

    STAGE(0, 0);
    __syncthreads();
    int cur = 0;

    for (int kt = 0; kt < 32; ++kt) {
        if (kt < 31) STAGE(cur ^ 1, kt + 1);   // prefetch next tile under compute

        // S = K_tile @ Q^T, TWO interleaved chains (halves of the d-dimension)
        f32x16 stA, stB;
#pragma unroll
        for (int j = 0; j < 16; j++) { stA[j] = 0.f; stB[j] = 0.f; }
        __builtin_amdgcn_s_setprio(1);
#pragma unroll
        for (int ks = 0; ks < 8; ks++) {
            s16x8 kfA = *(const s16x8*)(&Klds[cur][ks * 512 + l * 8]);
            s16x8 kfB = *(const s16x8*)(&Klds[cur][(ks + 8) * 512 + l * 8]);
            stA = __builtin_amdgcn_mfma_f32_32x32x16_bf16(kfA, qf[ks], stA, 0, 0, 0);
            stB = __builtin_amdgcn_mfma_f32_32x32x16_bf16(kfB, qf[ks + 8], stB, 0, 0, 0);
        }
        __builtin_amdgcn_s_setprio(0);

        // p = exp2(stA+stB) (Q pre-scaled); pack to bf16 pairs; sum into l_part
        u32 c0, c1, c2, c3, c4, c5, c6, c7;
        {
            f32x16 st = stA + stB;
            float pa0 = __builtin_amdgcn_exp2f(st[0]),  pa1 = __builtin_amdgcn_exp2f(st[1]);
            float pa2 = __builtin_amdgcn_exp2f(st[2]),  pa3 = __builtin_amdgcn_exp2f(st[3]);
            float pa4 = __builtin_amdgcn_exp2f(st[4]),  pa5 = __builtin_amdgcn_exp2f(st[5]);
            float pa6 = __builtin_amdgcn_exp2f(st[6]),  pa7 = __builtin_amdgcn_exp2f(st[7]);
            float pa8 = __builtin_amdgcn_exp2f(st[8]),  pa9 = __builtin_amdgcn_exp2f(st[9]);
            float paA = __builtin_amdgcn_exp2f(st[10]), paB = __builtin_amdgcn_exp2f(st[11]);
            float paC = __builtin_amdgcn_exp2f(st[12]), paD = __builtin_amdgcn_exp2f(st[13]);
            float paE = __builtin_amdgcn_exp2f(st[14]), paF = __builtin_amdgcn_exp2f(st[15]);
            l_part += (((pa0 + pa1) + (pa2 + pa3)) + ((pa4 + pa5) + (pa6 + pa7)))
                    + (((pa8 + pa9) + (paA + paB)) + ((paC + paD) + (paE + paF)));
            c0 = cvtpk_bf16(pa0, pa1); c1 = cvtpk_bf16(pa2, pa3);
            c2 = cvtpk_bf16(pa4, pa5); c3 = cvtpk_bf16(pa6, pa7);
            c4 = cvtpk_bf16(pa8, pa9); c5 = cvtpk_bf16(paA, paB);
            c6 = cvtpk_bf16(paC, paD); c7 = cvtpk_bf16(paE, paF);
        }
        // redistribute: after swap, c0..c3 = PA frag (keys 0-15), c4..c7 = keys 16-31
        asm("v_permlane32_swap_b32 %0, %1" : "+v"(c0), "+v"(c2));
        asm("v_permlane32_swap_b32 %0, %1" : "+v"(c1), "+v"(c3));
        asm("v_permlane32_swap_b32 %0, %1" : "+v"(c4), "+v"(c6));
        asm("v_permlane32_swap_b32 %0, %1" : "+v"(c5), "+v"(c7));
        struct { u32 a, b, c, d; } x0 = {c0, c1, c2, c3};
        struct { u32 a, b, c, d; } x1 = {c4, c5, c6, c7};
        s16x8 pa0f = __builtin_bit_cast(s16x8, x0);
        s16x8 pa1f = __builtin_bit_cast(s16x8, x1);

        // O += P @ V   (V from frag-major LDS; contiguous conflict-free reads;
        // 8 independent o-chains)
        __builtin_amdgcn_s_setprio(1);
#pragma unroll
        for (int ks = 0; ks < 2; ks++) {
            s16x8 paf = ks ? pa1f : pa0f;
#pragma unroll
            for (int nt = 0; nt < 8; nt++) {
                s16x8 bv = *(const s16x8*)(&Vlds[cur][(nt * 2 + ks) * 512 + l * 8]);
                o[nt] = __builtin_amdgcn_mfma_f32_32x32x16_bf16(paf, bv, o[nt], 0, 0, 0);
            }
        }
        __builtin_amdgcn_s_setprio(0);

        __syncthreads();   // drains vmcnt(0): next tile staged; cur reusable
        cur ^= 1;
    }
#undef STAGE

    // epilogue: lane owns l_part for q = l31 (its 16 keys) + partner half
    float lt = l_part + __shfl_xor(l_part, 32);
    float rinv = 1.0f / lt;
    float ri[16];
#pragma unroll
    for (int reg = 0; reg < 16; reg++) {
        int qr = (reg & 3) + 8 * (reg >> 2) + 4 * hi;
        ri[reg] = __shfl(rinv, qr);
    }
#pragma unroll
    for (int nt = 0; nt < 8; nt++) {
#pragma unroll
        for (int reg = 0; reg < 16; reg++) {
            int qr = (reg & 3) + 8 * (reg >> 2) + 4 * hi;
            O[(qrow0 + w * 32 + qr) * ldo + nt * 32 + l31] = f2bf(o[nt][reg] * ri[reg]);
        }
    }
}

// ---------------- host ----------------

extern "C" void kernel_launch(void* const* d_in, const int* in_sizes, int n_in,
                              void* d_out, int out_size, void* d_ws, size_t ws_size,
                              hipStream_t stream) {
    const float* x  = (const float*)d_in[0];
    const float* Wq = (const float*)d_in[1];
    const float* Wk = (const float*)d_in[2];
    const float* Wo = (const float*)d_in[3];
    float* out = (float*)d_out;
    char* ws = (char*)d_ws;

    unsigned short* xb  = (unsigned short*)(ws);
    unsigned short* wqt = (unsigned short*)(ws + 8388608);
    unsigned short* wkt = (unsigned short*)(ws + 9699328);
    unsigned short* wob = (unsigned short*)(ws + 11010048);
    char* dyn = ws + 12320768;

    cast_f32_bf16<<<4096, 256, 0, stream>>>(x, xb, BS_TOT * DIM);
    cast_f32_bf16<<<640, 256, 0, stream>>>(Wo, wob, DIM * HD);
    transpose_cast_w<<<dim3(8, 8, 2 * NH), 256, 0, stream>>>(Wq, Wk, wqt, wkt);

    const long perHeadElems = (long)BS_TOT * DIM;                // 4,194,304 (8MB bf16)
    const size_t FULL_NEED = 12320768ULL + 3ULL * 83886080ULL;   // ~264 MB (proven fits)

    if (ws_size >= FULL_NEED) {
        unsigned short* Qb  = (unsigned short*)dyn;              // also O (aliased)
        unsigned short* KQb = Qb + (long)NH * perHeadElems;
        unsigned short* KTb = KQb + (long)NH * perHeadElems;
        proj128<<<5120, 256, 0, stream>>>(xb, wqt, wkt, Qb, KQb, KTb,
                                          perHeadElems, perHeadElems);
        attn_kernel<<<1280, 256, 0, stream>>>(Qb, KQb, perHeadElems, KTb, perHeadElems,
                                              Qb, 256, perHeadElems, 160);
        final128<<<256, 256, 0, stream>>>(Qb, perHeadElems, wob, out);
    } else {
        unsigned short* Qh  = (unsigned short*)dyn;              // also O (aliased)
        unsigned short* KQh = Qh + perHeadElems;
        unsigned short* KTh = KQh + perHeadElems;
        hipMemsetAsync(d_out, 0, (size_t)out_size * 4, stream);
        for (int h = 0; h < NH; ++h) {
            proj_kernel<<<dim3(256, 1, 2), 256, 0, stream>>>(xb, wqt, wkt, Qh, KQh, KTh, h, 0, 0);
            attn_kernel<<<128, 256, 0, stream>>>(Qh, KQh, 0, KTh, 0, Qh, 256, 0, 16);
            final_kernel<<<256, 256, 0, stream>>>(Qh, 256, wob + h * 256, HD, out, 256, 1);
        }
    }
}

// Round 14
// 343.032 us; speedup vs baseline: 1.1329x; 1.0199x over previous
//
#include <hip/hip_runtime.h>

typedef float f32x4 __attribute__((ext_vector_type(4)));
typedef float f32x16 __attribute__((ext_vector_type(16)));
typedef short s16x8 __attribute__((ext_vector_type(8)));
typedef unsigned int u32;

#define BSZ 4
#define SEQ 4096
#define DIM 256
#define NH 10
#define NG 4
#define CHK 1024
#define BS_TOT 16384   // BSZ*SEQ
#define HD 2560        // NH*DIM
#define LOG2E 1.44269504f

__device__ __forceinline__ unsigned short f2bf(float f) {
    unsigned int u = __builtin_bit_cast(unsigned int, f);
    u = (u + 0x7fffu + ((u >> 16) & 1u)) >> 16;
    return (unsigned short)u;
}

__device__ __forceinline__ void gload_lds16(const unsigned short* g, unsigned short* l) {
    __builtin_amdgcn_global_load_lds((const __attribute__((address_space(1))) u32*)g,
                                     (__attribute__((address_space(3))) u32*)l, 16, 0, 0);
}

__device__ __forceinline__ u32 cvtpk_bf16(float lo, float hi) {
    u32 r;
    asm("v_cvt_pk_bf16_f32 %0, %1, %2" : "=v"(r) : "v"(lo), "v"(hi));
    return r;
}

// Frag-major global layouts, per (b,g) chunk, per 32-key tile (8192 elems = 16KB):
//  KQv (QK A-frags):  off(key,d) = (d>>4)*512 + ((d>>3)&1)*256 + (key&31)*8 + (d&7)
//  KTv (PV B-frags):  off(key,d) = (d>>5)*1024 + (key>>4)*512 + ((key>>3)&1)*256 + (d&31)*8 + (key&7)
// Each chunk = contiguous 512 elems (1KB) = one wave's gload_lds16 / ds_read_b128 span.

// ---------------- cast / transpose helpers ----------------

__global__ __launch_bounds__(256) void cast_f32_bf16(const float* __restrict__ s,
                                                     unsigned short* __restrict__ d, int n) {
    long i = 4L * (blockIdx.x * 256 + threadIdx.x);
    if (i < n) {
        float4 v = *(const float4*)(s + i);
        ushort4 o;
        o.x = f2bf(v.x); o.y = f2bf(v.y); o.z = f2bf(v.z); o.w = f2bf(v.w);
        *(ushort4*)(d + i) = o;
    }
}

// Wt[h][e][d] = W[h][d][e], fp32 -> bf16.  grid (8,8,2*NH), block 256
__global__ __launch_bounds__(256) void transpose_cast_w(const float* __restrict__ Wq,
                                                        const float* __restrict__ Wk,
                                                        unsigned short* __restrict__ wqt,
                                                        unsigned short* __restrict__ wkt) {
    const float* W = (blockIdx.z & 1) ? Wk : Wq;
    unsigned short* Wt = (blockIdx.z & 1) ? wkt : wqt;
    int h = blockIdx.z >> 1;
    __shared__ float tile[32][33];
    int d0 = blockIdx.x * 32, e0 = blockIdx.y * 32;
    int tx = threadIdx.x & 31, ty = threadIdx.x >> 5;
    const float* Wh = W + (long)h * 65536;
    unsigned short* Wth = Wt + (long)h * 65536;
#pragma unroll
    for (int r = ty; r < 32; r += 8) tile[r][tx] = Wh[(long)(d0 + r) * 256 + e0 + tx];
    __syncthreads();
#pragma unroll
    for (int r = ty; r < 32; r += 8) Wth[(long)(e0 + r) * 256 + d0 + tx] = f2bf(tile[tx][r]);
}

// ---------------- fallback small-tile GEMM (per-head path only) ----------------

__device__ __forceinline__ void gemm_body(const unsigned short* __restrict__ A, long lda,
                                          const unsigned short* __restrict__ Bt, long ldb,
                                          unsigned short* Cb, float* Cf, long ldc,
                                          int K, bool accum, long mbase,
                                          unsigned short* KQo, unsigned short* KTo,
                                          float cscale) {
    __shared__ unsigned short As[64 * 40];
    __shared__ unsigned short Bs[256 * 40];
    const int t = threadIdx.x;
    const int w = t >> 6, l = t & 63, lr = l & 15, lg = l >> 4;

    f32x4 acc[16];
#pragma unroll
    for (int i = 0; i < 16; i++) acc[i] = (f32x4){0.f, 0.f, 0.f, 0.f};

    const int ar = t >> 2, akc = (t & 3) * 8;

    for (int k0 = 0; k0 < K; k0 += 32) {
        *(s16x8*)(&As[ar * 40 + akc]) = *(const s16x8*)(A + (mbase + ar) * lda + k0 + akc);
#pragma unroll
        for (int s = 0; s < 4; s++) {
            int n = s * 64 + (t >> 2);
            *(s16x8*)(&Bs[n * 40 + akc]) = *(const s16x8*)(Bt + (long)n * ldb + k0 + akc);
        }
        __syncthreads();
        s16x8 af = *(const s16x8*)(&As[(w * 16 + lr) * 40 + lg * 8]);
        __builtin_amdgcn_s_setprio(1);
#pragma unroll
        for (int nt = 0; nt < 16; nt++) {
            s16x8 bf = *(const s16x8*)(&Bs[(nt * 16 + lr) * 40 + lg * 8]);
            acc[nt] = __builtin_amdgcn_mfma_f32_16x16x32_bf16(af, bf, acc[nt], 0, 0, 0);
        }
        __builtin_amdgcn_s_setprio(0);
        __syncthreads();
    }
    long m0 = mbase + w * 16 + lg * 4;
    if (Cb || Cf) {
#pragma unroll
        for (int nt = 0; nt < 16; nt++) {
            int col = nt * 16 + lr;
#pragma unroll
            for (int r = 0; r < 4; r++) {
                long idx = (m0 + r) * ldc + col;
                if (Cb) {
                    Cb[idx] = f2bf(acc[nt][r] * cscale);
                } else {
                    float v = acc[nt][r];
                    if (accum) v += Cf[idx];
                    Cf[idx] = v;
                }
            }
        }
    }
    if (KQo) {
        int bg = (int)(m0 >> 10);
        int kin = (int)(m0 & 1023);
        int kt = kin >> 5, kw = kin & 31;
        unsigned short* tb = KQo + (long)bg * (256 * 1024) + (long)kt * 8192;
#pragma unroll
        for (int nt = 0; nt < 16; nt++) {
            int d = nt * 16 + lr;
            unsigned short* p = tb + (d >> 4) * 512 + ((d >> 3) & 1) * 256 + (d & 7);
#pragma unroll
            for (int r = 0; r < 4; r++) p[(kw + r) * 8] = f2bf(acc[nt][r]);
        }
    }
    if (KTo) {
        int bg = (int)(m0 >> 10);
        int key0 = (int)(m0 & 1023);
        int kt = key0 >> 5, kw = key0 & 31;   // kw % 4 == 0
        unsigned short* base = KTo + (long)bg * (256 * 1024) + (long)kt * 8192
                             + (kw >> 4) * 512 + ((kw >> 3) & 1) * 256 + (kw & 7);
#pragma unroll
        for (int nt = 0; nt < 16; nt++) {
            int col = nt * 16 + lr;
            ushort4 v;
            v.x = f2bf(acc[nt][0]); v.y = f2bf(acc[nt][1]);
            v.z = f2bf(acc[nt][2]); v.w = f2bf(acc[nt][3]);
            *(ushort4*)(base + (col >> 5) * 1024 + (col & 31) * 8) = v;
        }
    }
}

__global__ __launch_bounds__(256) void proj_kernel(const unsigned short* __restrict__ xb,
                                                   const unsigned short* __restrict__ wqt,
                                                   const unsigned short* __restrict__ wkt,
                                                   unsigned short* Qb, unsigned short* KQb,
                                                   unsigned short* KTb,
                                                   int h0, long headStrideOut, long headStrideKT) {
    int h = h0 + blockIdx.y;
    bool isK = (blockIdx.z != 0);
    const unsigned short* Bt = (isK ? wkt : wqt) + (long)h * 65536;
    unsigned short* C = isK ? nullptr : (Qb + (long)blockIdx.y * headStrideOut);
    unsigned short* KQo = isK ? (KQb + (long)blockIdx.y * headStrideKT) : nullptr;
    unsigned short* KTo = isK ? (KTb + (long)blockIdx.y * headStrideKT) : nullptr;
    gemm_body(xb, 256, Bt, 256, C, nullptr, 256, 256, false, (long)blockIdx.x * 64,
              KQo, KTo, isK ? 1.0f : LOG2E);
}

__global__ __launch_bounds__(256) void final_kernel(const unsigned short* __restrict__ Ob, long lda,
                                                    const unsigned short* __restrict__ wob, long ldb,
                                                    float* out, int K, int accum) {
    gemm_body(Ob, lda, wob, ldb, nullptr, out, 256, K, accum != 0, (long)blockIdx.x * 64,
              nullptr, nullptr, 1.0f);
}

// ---------------- fused Q+K projection, 128x128 tiles ----------------
// One block computes BOTH Q[mtile][ntile] and K[mtile][ntile] for head h:
// the x A-tile is staged ONCE and feeds both Wq and Wk B-tiles (2x MFMA per
// staging byte vs separate blocks; half the blocks, prologue, barriers).
// grid 2560 = 128 mtiles x 10 heads x 2 ntiles, XCD-chunked (320/xcd).
// Q written row-major pre-scaled by log2e; K written as KQv + KTv frag-major.

__global__ __launch_bounds__(256, 2) void projQK(const unsigned short* __restrict__ xb,
                                                 const unsigned short* __restrict__ wqt,
                                                 const unsigned short* __restrict__ wkt,
                                                 unsigned short* __restrict__ Qb,
                                                 unsigned short* __restrict__ KQb,
                                                 unsigned short* __restrict__ KTb,
                                                 long headStrideOut, long headStrideKT) {
    __shared__ unsigned short As[2][128 * 32];
    __shared__ unsigned short Bqs[2][128 * 32];
    __shared__ unsigned short Bks[2][128 * 32];

    const int lb = blockIdx.x;
    const int logical = (lb & 7) * 320 + (lb >> 3);
    const int x = logical / 20;
    const int u = logical - x * 20;
    const int h = u >> 1, ntile = u & 1;

    const unsigned short* Bq = wqt + (long)h * 65536 + (long)ntile * 128 * 256;
    const unsigned short* Bk = wkt + (long)h * 65536 + (long)ntile * 128 * 256;
    const long mbase = (long)x * 128;
    const int ncol0 = ntile * 128;

    const int t = threadIdx.x, w = t >> 6, l = t & 63, lr = l & 15, lg = l >> 4;
    const int wm = w >> 1, wn = w & 1;

    int sOff[2];
#pragma unroll
    for (int i = 0; i < 2; i++) {
        int row = w * 32 + i * 16 + (l >> 2);
        int cs2 = (l & 3) ^ (row & 3);
        sOff[i] = row * 256 + cs2 * 8;
    }

    f32x4 accQ[4][4], accK[4][4];
#pragma unroll
    for (int i = 0; i < 4; i++)
#pragma unroll
        for (int j = 0; j < 4; j++) {
            accQ[i][j] = (f32x4){0.f, 0.f, 0.f, 0.f};
            accK[i][j] = (f32x4){0.f, 0.f, 0.f, 0.f};
        }

#define PSTAGE(buf, k0) do {                                                     \
        _Pragma("unroll")                                                        \
        for (int i = 0; i < 2; i++) {                                            \
            gload_lds16(xb + mbase * 256 + (k0) + sOff[i],                       \
                        &As[buf][(w * 32 + i * 16) * 32]);                       \
            gload_lds16(Bq + (k0) + sOff[i], &Bqs[buf][(w * 32 + i * 16) * 32]); \
            gload_lds16(Bk + (k0) + sOff[i], &Bks[buf][(w * 32 + i * 16) * 32]); \
        }                                                                        \
    } while (0)

    PSTAGE(0, 0);
    __syncthreads();
    int cur = 0;
    for (int ks = 0; ks < 8; ++ks) {
        if (ks < 7) PSTAGE(cur ^ 1, (ks + 1) * 32);
        s16x8 a[4], bq[4], bk[4];
#pragma unroll
        for (int mf = 0; mf < 4; mf++) {
            int row = wm * 64 + mf * 16 + lr;
            a[mf] = *(const s16x8*)(&As[cur][row * 32 + (lg ^ (row & 3)) * 8]);
        }
#pragma unroll
        for (int nf = 0; nf < 4; nf++) {
            int row = wn * 64 + nf * 16 + lr;
            int off = row * 32 + (lg ^ (row & 3)) * 8;
            bq[nf] = *(const s16x8*)(&Bqs[cur][off]);
            bk[nf] = *(const s16x8*)(&Bks[cur][off]);
        }
        __builtin_amdgcn_s_setprio(1);
#pragma unroll
        for (int mf = 0; mf < 4; mf++)
#pragma unroll
            for (int nf = 0; nf < 4; nf++) {
                accQ[mf][nf] = __builtin_amdgcn_mfma_f32_16x16x32_bf16(a[mf], bq[nf], accQ[mf][nf], 0, 0, 0);
                accK[mf][nf] = __builtin_amdgcn_mfma_f32_16x16x32_bf16(a[mf], bk[nf], accK[mf][nf], 0, 0, 0);
            }
        __builtin_amdgcn_s_setprio(0);
        __syncthreads();
        cur ^= 1;
    }
#undef PSTAGE

    long m0 = mbase + wm * 64 + lg * 4;
    // Q epilogue: row-major, pre-scaled by log2e
    {
        unsigned short* C = Qb + (long)h * headStrideOut;
#pragma unroll
        for (int mf = 0; mf < 4; mf++) {
            long mrow = m0 + mf * 16;
#pragma unroll
            for (int nf = 0; nf < 4; nf++) {
                int col = ncol0 + wn * 64 + nf * 16 + lr;
#pragma unroll
                for (int r = 0; r < 4; r++)
                    C[(mrow + r) * 256 + col] = f2bf(accQ[mf][nf][r] * LOG2E);
            }
        }
    }
    // K epilogue: KQv (scalar, d-inner) + KTv (vectorized, key-inner)
    {
        unsigned short* KQo = KQb + (long)h * headStrideKT;
        unsigned short* KTo = KTb + (long)h * headStrideKT;
#pragma unroll
        for (int mf = 0; mf < 4; mf++) {
            long key = m0 + mf * 16;
            int bg = (int)(key >> 10), kin = (int)(key & 1023);
            int kt = kin >> 5, kw = kin & 31;
            unsigned short* qtb = KQo + (long)bg * (256 * 1024) + (long)kt * 8192;
            unsigned short* vtb = KTo + (long)bg * (256 * 1024) + (long)kt * 8192
                                + (kw >> 4) * 512 + ((kw >> 3) & 1) * 256 + (kw & 7);
#pragma unroll
            for (int nf = 0; nf < 4; nf++) {
                int d = ncol0 + wn * 64 + nf * 16 + lr;
                unsigned short* p = qtb + (d >> 4) * 512 + ((d >> 3) & 1) * 256 + (d & 7);
#pragma unroll
                for (int r = 0; r < 4; r++) p[(kw + r) * 8] = f2bf(accK[mf][nf][r]);
                ushort4 v;
                v.x = f2bf(accK[mf][nf][0]); v.y = f2bf(accK[mf][nf][1]);
                v.z = f2bf(accK[mf][nf][2]); v.w = f2bf(accK[mf][nf][3]);
                *(ushort4*)(vtb + (d >> 5) * 1024 + (d & 31) * 8) = v;
            }
        }
    }
}

// ---------------- m97-style 128x128 GEMM: final projection ----------------

__global__ __launch_bounds__(256, 3) void final128(const unsigned short* __restrict__ Ob,
                                                   long headStride,
                                                   const unsigned short* __restrict__ wob,
                                                   float* __restrict__ out) {
    __shared__ unsigned short As[2][128 * 32];
    __shared__ unsigned short Bs[2][128 * 32];

    const int lb = blockIdx.x;
    const int logical = (lb & 7) * 32 + (lb >> 3);
    const int x = logical >> 1, ntile = logical & 1;
    const long mbase = (long)x * 128;
    const int ncol0 = ntile * 128;
    const unsigned short* Bt = wob + (long)ncol0 * HD;

    const int t = threadIdx.x, w = t >> 6, l = t & 63, lr = l & 15, lg = l >> 4;
    const int wm = w >> 1, wn = w & 1;

    int sOffA[2], sOffB[2];
#pragma unroll
    for (int i = 0; i < 2; i++) {
        int row = w * 32 + i * 16 + (l >> 2);
        int cs2 = (l & 3) ^ (row & 3);
        sOffA[i] = row * 256 + cs2 * 8;
        sOffB[i] = row * HD + cs2 * 8;
    }

    f32x4 acc[4][4];
#pragma unroll
    for (int i = 0; i < 4; i++)
#pragma unroll
        for (int j = 0; j < 4; j++) acc[i][j] = (f32x4){0.f, 0.f, 0.f, 0.f};

#define FSTAGE(buf, k0) do {                                                     \
        const unsigned short* Asrc = Ob + (long)((k0) >> 8) * headStride         \
                                   + mbase * 256 + ((k0) & 255);                 \
        _Pragma("unroll")                                                        \
        for (int i = 0; i < 2; i++)                                              \
            gload_lds16(Asrc + sOffA[i], &As[buf][(w * 32 + i * 16) * 32]);      \
        _Pragma("unroll")                                                        \
        for (int i = 0; i < 2; i++)                                              \
            gload_lds16(Bt + (k0) + sOffB[i], &Bs[buf][(w * 32 + i * 16) * 32]); \
    } while (0)

    FSTAGE(0, 0);
    __syncthreads();
    int cur = 0;
    for (int ks = 0; ks < 80; ++ks) {
        if (ks < 79) FSTAGE(cur ^ 1, (ks + 1) * 32);
        s16x8 a[4], b[4];
#pragma unroll
        for (int mf = 0; mf < 4; mf++) {
            int row = wm * 64 + mf * 16 + lr;
            a[mf] = *(const s16x8*)(&As[cur][row * 32 + (lg ^ (row & 3)) * 8]);
        }
#pragma unroll
        for (int nf = 0; nf < 4; nf++) {
            int row = wn * 64 + nf * 16 + lr;
            b[nf] = *(const s16x8*)(&Bs[cur][row * 32 + (lg ^ (row & 3)) * 8]);
        }
        __builtin_amdgcn_s_setprio(1);
#pragma unroll
        for (int mf = 0; mf < 4; mf++)
#pragma unroll
            for (int nf = 0; nf < 4; nf++)
                acc[mf][nf] = __builtin_amdgcn_mfma_f32_16x16x32_bf16(a[mf], b[nf], acc[mf][nf], 0, 0, 0);
        __builtin_amdgcn_s_setprio(0);
        __syncthreads();
        cur ^= 1;
    }
#undef FSTAGE

    long m0 = mbase + wm * 64 + lg * 4;
#pragma unroll
    for (int mf = 0; mf < 4; mf++) {
        long mrow = m0 + mf * 16;
#pragma unroll
        for (int nf = 0; nf < 4; nf++) {
            int col = ncol0 + wn * 64 + nf * 16 + lr;
#pragma unroll
            for (int r = 0; r < 4; r++) out[(mrow + r) * 256 + col] = acc[mf][nf][r];
        }
    }
}

// ---------------- attention (32x32 MFMA, frag-major LDS) — round-10 form ------
// Best measured: 197us attn, 0 bank conflicts, ~85% of LDS-port roofline.
// 1D grid 1280, block 256 (4 waves), q=32/wave, ~2 waves/SIMD.
// XCD-chunked: logical = (lb&7)*160 + (lb>>3); -> bx(8) | by(16) | h.
// chunk g attends KV chunk (g+1)%4.  V == K.  Q pre-scaled by log2e -> p = exp2(S).

__global__ __launch_bounds__(256, 2) void attn_kernel(const unsigned short* __restrict__ Qb,
                                                      const unsigned short* __restrict__ KQg,
                                                      long headStrideQK,
                                                      const unsigned short* __restrict__ KTg,
                                                      long headStrideKT,
                                                      unsigned short* __restrict__ Ob,
                                                      long ldo, long colStride,
                                                      int chunkPerXcd) {
    const int lb = blockIdx.x;
    const int logical = (lb & 7) * chunkPerXcd + (lb >> 3);
    const int bx = logical & 7;
    const int by = (logical >> 3) & 15;
    const int h = logical >> 7;

    const unsigned short* Q = Qb + (long)h * colStride;  // Q row-major per-head
    const unsigned short* KQ = KQg + (long)h * headStrideQK;
    const unsigned short* KT = KTg + (long)h * headStrideKT;
    unsigned short* O = Ob + (long)h * colStride;
    const int b = by >> 2, g = by & 3;
    const long qrow0 = (long)b * SEQ + (long)g * CHK + (long)bx * 128;
    const int bgk = b * NG + ((g + 1) & 3);
    const unsigned short* KQc = KQ + (long)bgk * (256 * 1024);
    const unsigned short* KTc = KT + (long)bgk * (256 * 1024);

    __shared__ unsigned short Klds[2][8192];  // 2 x 16KB, frag-major
    __shared__ unsigned short Vlds[2][8192];  // 2 x 16KB, frag-major

    const int t = threadIdx.x;
    const int w = t >> 6, l = t & 63, l31 = l & 31, hi = l >> 5;

    // Q fragments (B-operand, 32x32x16): lane holds Q[q = l31][d = s*16 + hi*8 + j]
    s16x8 qf[16];
    {
        const unsigned short* qp = Q + (qrow0 + w * 32 + l31) * 256 + hi * 8;
#pragma unroll
        for (int s = 0; s < 16; s++) qf[s] = *(const s16x8*)(qp + s * 16);
    }

    f32x16 o[8];
#pragma unroll
    for (int i = 0; i < 8; i++)
#pragma unroll
        for (int j = 0; j < 16; j++) o[i][j] = 0.f;
    float l_part = 0.f;

#define STAGE(buf, kt_) do {                                                    \
        const unsigned short* Ks = KQc + (long)(kt_) * 8192 + l * 8;            \
        const unsigned short* Vs = KTc + (long)(kt_) * 8192 + l * 8;            \
        _Pragma("unroll")                                                       \
        for (int i = 0; i < 4; i++) {                                           \
            int c = w * 4 + i;                                                  \
            gload_lds16(Ks + c * 512, &Klds[buf][c * 512]);                     \
            gload_lds16(Vs + c * 512, &Vlds[buf][c * 512]);                     \
        }                                                                       \
    } while (0)

    STAGE(0, 0);
    __syncthreads();
    int cur = 0;

    for (int kt = 0; kt < 32; ++kt) {
        if (kt < 31) STAGE(cur ^ 1, kt + 1);   // prefetch next tile under compute

        // S = K_tile @ Q^T  (32x32 keys x q), lane col q = l31
        f32x16 st;
#pragma unroll
        for (int j = 0; j < 16; j++) st[j] = 0.f;
        __builtin_amdgcn_s_setprio(1);
#pragma unroll
        for (int ks = 0; ks < 16; ks++) {
            s16x8 kf = *(const s16x8*)(&Klds[cur][ks * 512 + l * 8]);
            st = __builtin_amdgcn_mfma_f32_32x32x16_bf16(kf, qf[ks], st, 0, 0, 0);
        }
        __builtin_amdgcn_s_setprio(0);

        // p = exp2(S) (Q pre-scaled); pack to bf16 pairs; sum into l_part
        u32 c0, c1, c2, c3, c4, c5, c6, c7;
        {
            float pa0 = __builtin_amdgcn_exp2f(st[0]),  pa1 = __builtin_amdgcn_exp2f(st[1]);
            float pa2 = __builtin_amdgcn_exp2f(st[2]),  pa3 = __builtin_amdgcn_exp2f(st[3]);
            float pa4 = __builtin_amdgcn_exp2f(st[4]),  pa5 = __builtin_amdgcn_exp2f(st[5]);
            float pa6 = __builtin_amdgcn_exp2f(st[6]),  pa7 = __builtin_amdgcn_exp2f(st[7]);
            float pa8 = __builtin_amdgcn_exp2f(st[8]),  pa9 = __builtin_amdgcn_exp2f(st[9]);
            float paA = __builtin_amdgcn_exp2f(st[10]), paB = __builtin_amdgcn_exp2f(st[11]);
            float paC = __builtin_amdgcn_exp2f(st[12]), paD = __builtin_amdgcn_exp2f(st[13]);
            float paE = __builtin_amdgcn_exp2f(st[14]), paF = __builtin_amdgcn_exp2f(st[15]);
            l_part += (((pa0 + pa1) + (pa2 + pa3)) + ((pa4 + pa5) + (pa6 + pa7)))
                    + (((pa8 + pa9) + (paA + paB)) + ((paC + paD) + (paE + paF)));
            c0 = cvtpk_bf16(pa0, pa1); c1 = cvtpk_bf16(pa2, pa3);
            c2 = cvtpk_bf16(pa4, pa5); c3 = cvtpk_bf16(pa6, pa7);
            c4 = cvtpk_bf16(pa8, pa9); c5 = cvtpk_bf16(paA, paB);
            c6 = cvtpk_bf16(paC, paD); c7 = cvtpk_bf16(paE, paF);
        }
        // redistribute: after swap, c0..c3 = PA frag (keys 0-15), c4..c7 = keys 16-31
        asm("v_permlane32_swap_b32 %0, %1" : "+v"(c0), "+v"(c2));
        asm("v_permlane32_swap_b32 %0, %1" : "+v"(c1), "+v"(c3));
        asm("v_permlane32_swap_b32 %0, %1" : "+v"(c4), "+v"(c6));
        asm("v_permlane32_swap_b32 %0, %1" : "+v"(c5), "+v"(c7));
        struct { u32 a, b, c, d; } x0 = {c0, c1, c2, c3};
        struct { u32 a, b, c, d; } x1 = {c4, c5, c6, c7};
        s16x8 pa0f = __builtin_bit_cast(s16x8, x0);
        s16x8 pa1f = __builtin_bit_cast(s16x8, x1);

        // O += P @ V   (V from frag-major LDS; contiguous conflict-free reads)
        __builtin_amdgcn_s_setprio(1);
#pragma unroll
        for (int ks = 0; ks < 2; ks++) {
            s16x8 paf = ks ? pa1f : pa0f;
#pragma unroll
            for (int nt = 0; nt < 8; nt++) {
                s16x8 bv = *(const s16x8*)(&Vlds[cur][(nt * 2 + ks) * 512 + l * 8]);
                o[nt] = __builtin_amdgcn_mfma_f32_32x32x16_bf16(paf, bv, o[nt], 0, 0, 0);
            }
        }
        __builtin_amdgcn_s_setprio(0);

        __syncthreads();   // drains vmcnt(0): next tile staged; cur reusable
        cur ^= 1;
    }
#undef STAGE

    // epilogue: lane owns l_part for q = l31 (its 16 keys) + partner half
    float lt = l_part + __shfl_xor(l_part, 32);
    float rinv = 1.0f / lt;
    float ri[16];
#pragma unroll
    for (int reg = 0; reg < 16; reg++) {
        int qr = (reg & 3) + 8 * (reg >> 2) + 4 * hi;
        ri[reg] = __shfl(rinv, qr);
    }
#pragma unroll
    for (int nt = 0; nt < 8; nt++) {
#pragma unroll
        for (int reg = 0; reg < 16; reg++) {
            int qr = (reg & 3) + 8 * (reg >> 2) + 4 * hi;
            O[(qrow0 + w * 32 + qr) * ldo + nt * 32 + l31] = f2bf(o[nt][reg] * ri[reg]);
        }
    }
}

// ---------------- host ----------------

extern "C" void kernel_launch(void* const* d_in, const int* in_sizes, int n_in,
                              void* d_out, int out_size, void* d_ws, size_t ws_size,
                              hipStream_t stream) {
    const float* x  = (const float*)d_in[0];
    const float* Wq = (const float*)d_in[1];
    const float* Wk = (const float*)d_in[2];
    const float* Wo = (const float*)d_in[3];
    float* out = (float*)d_out;
    char* ws = (char*)d_ws;

    unsigned short* xb  = (unsigned short*)(ws);
    unsigned short* wqt = (unsigned short*)(ws + 8388608);
    unsigned short* wkt = (unsigned short*)(ws + 9699328);
    unsigned short* wob = (unsigned short*)(ws + 11010048);
    char* dyn = ws + 12320768;

    cast_f32_bf16<<<4096, 256, 0, stream>>>(x, xb, BS_TOT * DIM);
    cast_f32_bf16<<<640, 256, 0, stream>>>(Wo, wob, DIM * HD);
    transpose_cast_w<<<dim3(8, 8, 2 * NH), 256, 0, stream>>>(Wq, Wk, wqt, wkt);

    const long perHeadElems = (long)BS_TOT * DIM;                // 4,194,304 (8MB bf16)
    const size_t FULL_NEED = 12320768ULL + 3ULL * 83886080ULL;   // ~264 MB (proven fits)

    if (ws_size >= FULL_NEED) {
        unsigned short* Qb  = (unsigned short*)dyn;              // also O (aliased)
        unsigned short* KQb = Qb + (long)NH * perHeadElems;
        unsigned short* KTb = KQb + (long)NH * perHeadElems;
        projQK<<<2560, 256, 0, stream>>>(xb, wqt, wkt, Qb, KQb, KTb,
                                         perHeadElems, perHeadElems);
        attn_kernel<<<1280, 256, 0, stream>>>(Qb, KQb, perHeadElems, KTb, perHeadElems,
                                              Qb, 256, perHeadElems, 160);
        final128<<<256, 256, 0, stream>>>(Qb, perHeadElems, wob, out);
    } else {
        unsigned short* Qh  = (unsigned short*)dyn;              // also O (aliased)
        unsigned short* KQh = Qh + perHeadElems;
        unsigned short* KTh = KQh + perHeadElems;
        hipMemsetAsync(d_out, 0, (size_t)out_size * 4, stream);
        for (int h = 0; h < NH; ++h) {
            proj_kernel<<<dim3(256, 1, 2), 256, 0, stream>>>(xb, wqt, wkt, Qh, KQh, KTh, h, 0, 0);
            attn_kernel<<<128, 256, 0, stream>>>(Qh, KQh, 0, KTh, 0, Qh, 256, 0, 16);
            final_kernel<<<256, 256, 0, stream>>>(Qh, 256, wob + h * 256, HD, out, 256, 1);
        }
    }
}

// Round 15
// 338.968 us; speedup vs baseline: 1.1465x; 1.0120x over previous
//
#include <hip/hip_runtime.h>

typedef float f32x4 __attribute__((ext_vector_type(4)));
typedef float f32x16 __attribute__((ext_vector_type(16)));
typedef short s16x8 __attribute__((ext_vector_type(8)));
typedef unsigned int u32;

#define BSZ 4
#define SEQ 4096
#define DIM 256
#define NH 10
#define NG 4
#define CHK 1024
#define BS_TOT 16384   // BSZ*SEQ
#define HD 2560        // NH*DIM
#define LOG2E 1.44269504f

__device__ __forceinline__ unsigned short f2bf(float f) {
    unsigned int u = __builtin_bit_cast(unsigned int, f);
    u = (u + 0x7fffu + ((u >> 16) & 1u)) >> 16;
    return (unsigned short)u;
}

__device__ __forceinline__ void gload_lds16(const unsigned short* g, unsigned short* l) {
    __builtin_amdgcn_global_load_lds((const __attribute__((address_space(1))) u32*)g,
                                     (__attribute__((address_space(3))) u32*)l, 16, 0, 0);
}

__device__ __forceinline__ u32 cvtpk_bf16(float lo, float hi) {
    u32 r;
    asm("v_cvt_pk_bf16_f32 %0, %1, %2" : "=v"(r) : "v"(lo), "v"(hi));
    return r;
}

// Frag-major global layouts, per (b,g) chunk, per 32-key tile (8192 elems = 16KB):
//  KQv (QK A-frags):  off(key,d) = (d>>4)*512 + ((d>>3)&1)*256 + (key&31)*8 + (d&7)
//  KTv (PV B-frags):  off(key,d) = (d>>5)*1024 + (key>>4)*512 + ((key>>3)&1)*256 + (d&31)*8 + (key&7)
// Each chunk = contiguous 512 elems (1KB) = one wave's gload_lds16 / ds_read_b128 span.

// ---------------- fused prologue: x-cast | Wo-cast | Wq/Wk transpose ----------
// grid 6016: [0,4096) x-cast, [4096,4736) Wo-cast, [4736,6016) W-transpose.

__global__ __launch_bounds__(256) void prep(const float* __restrict__ x,
                                            const float* __restrict__ Wq,
                                            const float* __restrict__ Wk,
                                            const float* __restrict__ Wo,
                                            unsigned short* __restrict__ xb,
                                            unsigned short* __restrict__ wqt,
                                            unsigned short* __restrict__ wkt,
                                            unsigned short* __restrict__ wob) {
    __shared__ float tile[32][33];
    const int bid = blockIdx.x;
    if (bid < 4096) {
        long i = 4L * ((long)bid * 256 + threadIdx.x);
        float4 v = *(const float4*)(x + i);
        ushort4 o;
        o.x = f2bf(v.x); o.y = f2bf(v.y); o.z = f2bf(v.z); o.w = f2bf(v.w);
        *(ushort4*)(xb + i) = o;
    } else if (bid < 4736) {
        long i = 4L * ((long)(bid - 4096) * 256 + threadIdx.x);
        float4 v = *(const float4*)(Wo + i);
        ushort4 o;
        o.x = f2bf(v.x); o.y = f2bf(v.y); o.z = f2bf(v.z); o.w = f2bf(v.w);
        *(ushort4*)(wob + i) = o;
    } else {
        int u = bid - 4736;            // 1280 = 64 x (2*NH)
        int zz = u >> 6;               // 0..19
        int rest = u & 63;
        int bx = rest & 7, by = rest >> 3;
        const float* W = (zz & 1) ? Wk : Wq;
        unsigned short* Wt = (zz & 1) ? wkt : wqt;
        int h = zz >> 1;
        int d0 = bx * 32, e0 = by * 32;
        int tx = threadIdx.x & 31, ty = threadIdx.x >> 5;
        const float* Wh = W + (long)h * 65536;
        unsigned short* Wth = Wt + (long)h * 65536;
#pragma unroll
        for (int r = ty; r < 32; r += 8) tile[r][tx] = Wh[(long)(d0 + r) * 256 + e0 + tx];
        __syncthreads();
#pragma unroll
        for (int r = ty; r < 32; r += 8) Wth[(long)(e0 + r) * 256 + d0 + tx] = f2bf(tile[tx][r]);
    }
}

// ---------------- fallback small-tile GEMM (per-head path only) ----------------

__device__ __forceinline__ void gemm_body(const unsigned short* __restrict__ A, long lda,
                                          const unsigned short* __restrict__ Bt, long ldb,
                                          unsigned short* Cb, float* Cf, long ldc,
                                          int K, bool accum, long mbase,
                                          unsigned short* KQo, unsigned short* KTo,
                                          float cscale) {
    __shared__ unsigned short As[64 * 40];
    __shared__ unsigned short Bs[256 * 40];
    const int t = threadIdx.x;
    const int w = t >> 6, l = t & 63, lr = l & 15, lg = l >> 4;

    f32x4 acc[16];
#pragma unroll
    for (int i = 0; i < 16; i++) acc[i] = (f32x4){0.f, 0.f, 0.f, 0.f};

    const int ar = t >> 2, akc = (t & 3) * 8;

    for (int k0 = 0; k0 < K; k0 += 32) {
        *(s16x8*)(&As[ar * 40 + akc]) = *(const s16x8*)(A + (mbase + ar) * lda + k0 + akc);
#pragma unroll
        for (int s = 0; s < 4; s++) {
            int n = s * 64 + (t >> 2);
            *(s16x8*)(&Bs[n * 40 + akc]) = *(const s16x8*)(Bt + (long)n * ldb + k0 + akc);
        }
        __syncthreads();
        s16x8 af = *(const s16x8*)(&As[(w * 16 + lr) * 40 + lg * 8]);
        __builtin_amdgcn_s_setprio(1);
#pragma unroll
        for (int nt = 0; nt < 16; nt++) {
            s16x8 bf = *(const s16x8*)(&Bs[(nt * 16 + lr) * 40 + lg * 8]);
            acc[nt] = __builtin_amdgcn_mfma_f32_16x16x32_bf16(af, bf, acc[nt], 0, 0, 0);
        }
        __builtin_amdgcn_s_setprio(0);
        __syncthreads();
    }
    long m0 = mbase + w * 16 + lg * 4;
    if (Cb || Cf) {
#pragma unroll
        for (int nt = 0; nt < 16; nt++) {
            int col = nt * 16 + lr;
#pragma unroll
            for (int r = 0; r < 4; r++) {
                long idx = (m0 + r) * ldc + col;
                if (Cb) {
                    Cb[idx] = f2bf(acc[nt][r] * cscale);
                } else {
                    float v = acc[nt][r];
                    if (accum) v += Cf[idx];
                    Cf[idx] = v;
                }
            }
        }
    }
    if (KQo) {
        int bg = (int)(m0 >> 10);
        int kin = (int)(m0 & 1023);
        int kt = kin >> 5, kw = kin & 31;
        unsigned short* tb = KQo + (long)bg * (256 * 1024) + (long)kt * 8192;
#pragma unroll
        for (int nt = 0; nt < 16; nt++) {
            int d = nt * 16 + lr;
            unsigned short* p = tb + (d >> 4) * 512 + ((d >> 3) & 1) * 256 + (d & 7);
#pragma unroll
            for (int r = 0; r < 4; r++) p[(kw + r) * 8] = f2bf(acc[nt][r]);
        }
    }
    if (KTo) {
        int bg = (int)(m0 >> 10);
        int key0 = (int)(m0 & 1023);
        int kt = key0 >> 5, kw = key0 & 31;   // kw % 4 == 0
        unsigned short* base = KTo + (long)bg * (256 * 1024) + (long)kt * 8192
                             + (kw >> 4) * 512 + ((kw >> 3) & 1) * 256 + (kw & 7);
#pragma unroll
        for (int nt = 0; nt < 16; nt++) {
            int col = nt * 16 + lr;
            ushort4 v;
            v.x = f2bf(acc[nt][0]); v.y = f2bf(acc[nt][1]);
            v.z = f2bf(acc[nt][2]); v.w = f2bf(acc[nt][3]);
            *(ushort4*)(base + (col >> 5) * 1024 + (col & 31) * 8) = v;
        }
    }
}

__global__ __launch_bounds__(256) void proj_kernel(const unsigned short* __restrict__ xb,
                                                   const unsigned short* __restrict__ wqt,
                                                   const unsigned short* __restrict__ wkt,
                                                   unsigned short* Qb, unsigned short* KQb,
                                                   unsigned short* KTb,
                                                   int h0, long headStrideOut, long headStrideKT) {
    int h = h0 + blockIdx.y;
    bool isK = (blockIdx.z != 0);
    const unsigned short* Bt = (isK ? wkt : wqt) + (long)h * 65536;
    unsigned short* C = isK ? nullptr : (Qb + (long)blockIdx.y * headStrideOut);
    unsigned short* KQo = isK ? (KQb + (long)blockIdx.y * headStrideKT) : nullptr;
    unsigned short* KTo = isK ? (KTb + (long)blockIdx.y * headStrideKT) : nullptr;
    gemm_body(xb, 256, Bt, 256, C, nullptr, 256, 256, false, (long)blockIdx.x * 64,
              KQo, KTo, isK ? 1.0f : LOG2E);
}

__global__ __launch_bounds__(256) void final_kernel(const unsigned short* __restrict__ Ob, long lda,
                                                    const unsigned short* __restrict__ wob, long ldb,
                                                    float* out, int K, int accum) {
    gemm_body(Ob, lda, wob, ldb, nullptr, out, 256, K, accum != 0, (long)blockIdx.x * 64,
              nullptr, nullptr, 1.0f);
}

// ---------------- fused Q+K projection, 128x128 tiles ----------------
// One block computes BOTH Q[mtile][ntile] and K[mtile][ntile] for head h:
// the x A-tile is staged ONCE and feeds both Wq and Wk B-tiles.
// grid 2560 = 128 mtiles x 10 heads x 2 ntiles, XCD-chunked (320/xcd).
// Q written row-major pre-scaled by log2e; K written as KQv + KTv frag-major.

__global__ __launch_bounds__(256, 2) void projQK(const unsigned short* __restrict__ xb,
                                                 const unsigned short* __restrict__ wqt,
                                                 const unsigned short* __restrict__ wkt,
                                                 unsigned short* __restrict__ Qb,
                                                 unsigned short* __restrict__ KQb,
                                                 unsigned short* __restrict__ KTb,
                                                 long headStrideOut, long headStrideKT) {
    __shared__ unsigned short As[2][128 * 32];
    __shared__ unsigned short Bqs[2][128 * 32];
    __shared__ unsigned short Bks[2][128 * 32];

    const int lb = blockIdx.x;
    const int logical = (lb & 7) * 320 + (lb >> 3);
    const int x = logical / 20;
    const int u = logical - x * 20;
    const int h = u >> 1, ntile = u & 1;

    const unsigned short* Bq = wqt + (long)h * 65536 + (long)ntile * 128 * 256;
    const unsigned short* Bk = wkt + (long)h * 65536 + (long)ntile * 128 * 256;
    const long mbase = (long)x * 128;
    const int ncol0 = ntile * 128;

    const int t = threadIdx.x, w = t >> 6, l = t & 63, lr = l & 15, lg = l >> 4;
    const int wm = w >> 1, wn = w & 1;

    int sOff[2];
#pragma unroll
    for (int i = 0; i < 2; i++) {
        int row = w * 32 + i * 16 + (l >> 2);
        int cs2 = (l & 3) ^ (row & 3);
        sOff[i] = row * 256 + cs2 * 8;
    }

    f32x4 accQ[4][4], accK[4][4];
#pragma unroll
    for (int i = 0; i < 4; i++)
#pragma unroll
        for (int j = 0; j < 4; j++) {
            accQ[i][j] = (f32x4){0.f, 0.f, 0.f, 0.f};
            accK[i][j] = (f32x4){0.f, 0.f, 0.f, 0.f};
        }

#define PSTAGE(buf, k0) do {                                                     \
        _Pragma("unroll")                                                        \
        for (int i = 0; i < 2; i++) {                                            \
            gload_lds16(xb + mbase * 256 + (k0) + sOff[i],                       \
                        &As[buf][(w * 32 + i * 16) * 32]);                       \
            gload_lds16(Bq + (k0) + sOff[i], &Bqs[buf][(w * 32 + i * 16) * 32]); \
            gload_lds16(Bk + (k0) + sOff[i], &Bks[buf][(w * 32 + i * 16) * 32]); \
        }                                                                        \
    } while (0)

    PSTAGE(0, 0);
    __syncthreads();
    int cur = 0;
    for (int ks = 0; ks < 8; ++ks) {
        if (ks < 7) PSTAGE(cur ^ 1, (ks + 1) * 32);
        s16x8 a[4], bq[4], bk[4];
#pragma unroll
        for (int mf = 0; mf < 4; mf++) {
            int row = wm * 64 + mf * 16 + lr;
            a[mf] = *(const s16x8*)(&As[cur][row * 32 + (lg ^ (row & 3)) * 8]);
        }
#pragma unroll
        for (int nf = 0; nf < 4; nf++) {
            int row = wn * 64 + nf * 16 + lr;
            int off = row * 32 + (lg ^ (row & 3)) * 8;
            bq[nf] = *(const s16x8*)(&Bqs[cur][off]);
            bk[nf] = *(const s16x8*)(&Bks[cur][off]);
        }
        __builtin_amdgcn_s_setprio(1);
#pragma unroll
        for (int mf = 0; mf < 4; mf++)
#pragma unroll
            for (int nf = 0; nf < 4; nf++) {
                accQ[mf][nf] = __builtin_amdgcn_mfma_f32_16x16x32_bf16(a[mf], bq[nf], accQ[mf][nf], 0, 0, 0);
                accK[mf][nf] = __builtin_amdgcn_mfma_f32_16x16x32_bf16(a[mf], bk[nf], accK[mf][nf], 0, 0, 0);
            }
        __builtin_amdgcn_s_setprio(0);
        __syncthreads();
        cur ^= 1;
    }
#undef PSTAGE

    long m0 = mbase + wm * 64 + lg * 4;
    // Q epilogue: row-major, pre-scaled by log2e
    {
        unsigned short* C = Qb + (long)h * headStrideOut;
#pragma unroll
        for (int mf = 0; mf < 4; mf++) {
            long mrow = m0 + mf * 16;
#pragma unroll
            for (int nf = 0; nf < 4; nf++) {
                int col = ncol0 + wn * 64 + nf * 16 + lr;
#pragma unroll
                for (int r = 0; r < 4; r++)
                    C[(mrow + r) * 256 + col] = f2bf(accQ[mf][nf][r] * LOG2E);
            }
        }
    }
    // K epilogue: KQv (scalar, d-inner) + KTv (vectorized, key-inner)
    {
        unsigned short* KQo = KQb + (long)h * headStrideKT;
        unsigned short* KTo = KTb + (long)h * headStrideKT;
#pragma unroll
        for (int mf = 0; mf < 4; mf++) {
            long key = m0 + mf * 16;
            int bg = (int)(key >> 10), kin = (int)(key & 1023);
            int kt = kin >> 5, kw = kin & 31;
            unsigned short* qtb = KQo + (long)bg * (256 * 1024) + (long)kt * 8192;
            unsigned short* vtb = KTo + (long)bg * (256 * 1024) + (long)kt * 8192
                                + (kw >> 4) * 512 + ((kw >> 3) & 1) * 256 + (kw & 7);
#pragma unroll
            for (int nf = 0; nf < 4; nf++) {
                int d = ncol0 + wn * 64 + nf * 16 + lr;
                unsigned short* p = qtb + (d >> 4) * 512 + ((d >> 3) & 1) * 256 + (d & 7);
#pragma unroll
                for (int r = 0; r < 4; r++) p[(kw + r) * 8] = f2bf(accK[mf][nf][r]);
                ushort4 v;
                v.x = f2bf(accK[mf][nf][0]); v.y = f2bf(accK[mf][nf][1]);
                v.z = f2bf(accK[mf][nf][2]); v.w = f2bf(accK[mf][nf][3]);
                *(ushort4*)(vtb + (d >> 5) * 1024 + (d & 31) * 8) = v;
            }
        }
    }
}

// ---------------- m97-style 128x128 GEMM: final projection ----------------

__global__ __launch_bounds__(256, 3) void final128(const unsigned short* __restrict__ Ob,
                                                   long headStride,
                                                   const unsigned short* __restrict__ wob,
                                                   float* __restrict__ out) {
    __shared__ unsigned short As[2][128 * 32];
    __shared__ unsigned short Bs[2][128 * 32];

    const int lb = blockIdx.x;
    const int logical = (lb & 7) * 32 + (lb >> 3);
    const int x = logical >> 1, ntile = logical & 1;
    const long mbase = (long)x * 128;
    const int ncol0 = ntile * 128;
    const unsigned short* Bt = wob + (long)ncol0 * HD;

    const int t = threadIdx.x, w = t >> 6, l = t & 63, lr = l & 15, lg = l >> 4;
    const int wm = w >> 1, wn = w & 1;

    int sOffA[2], sOffB[2];
#pragma unroll
    for (int i = 0; i < 2; i++) {
        int row = w * 32 + i * 16 + (l >> 2);
        int cs2 = (l & 3) ^ (row & 3);
        sOffA[i] = row * 256 + cs2 * 8;
        sOffB[i] = row * HD + cs2 * 8;
    }

    f32x4 acc[4][4];
#pragma unroll
    for (int i = 0; i < 4; i++)
#pragma unroll
        for (int j = 0; j < 4; j++) acc[i][j] = (f32x4){0.f, 0.f, 0.f, 0.f};

#define FSTAGE(buf, k0) do {                                                     \
        const unsigned short* Asrc = Ob + (long)((k0) >> 8) * headStride         \
                                   + mbase * 256 + ((k0) & 255);                 \
        _Pragma("unroll")                                                        \
        for (int i = 0; i < 2; i++)                                              \
            gload_lds16(Asrc + sOffA[i], &As[buf][(w * 32 + i * 16) * 32]);      \
        _Pragma("unroll")                                                        \
        for (int i = 0; i < 2; i++)                                              \
            gload_lds16(Bt + (k0) + sOffB[i], &Bs[buf][(w * 32 + i * 16) * 32]); \
    } while (0)

    FSTAGE(0, 0);
    __syncthreads();
    int cur = 0;
    for (int ks = 0; ks < 80; ++ks) {
        if (ks < 79) FSTAGE(cur ^ 1, (ks + 1) * 32);
        s16x8 a[4], b[4];
#pragma unroll
        for (int mf = 0; mf < 4; mf++) {
            int row = wm * 64 + mf * 16 + lr;
            a[mf] = *(const s16x8*)(&As[cur][row * 32 + (lg ^ (row & 3)) * 8]);
        }
#pragma unroll
        for (int nf = 0; nf < 4; nf++) {
            int row = wn * 64 + nf * 16 + lr;
            b[nf] = *(const s16x8*)(&Bs[cur][row * 32 + (lg ^ (row & 3)) * 8]);
        }
        __builtin_amdgcn_s_setprio(1);
#pragma unroll
        for (int mf = 0; mf < 4; mf++)
#pragma unroll
            for (int nf = 0; nf < 4; nf++)
                acc[mf][nf] = __builtin_amdgcn_mfma_f32_16x16x32_bf16(a[mf], b[nf], acc[mf][nf], 0, 0, 0);
        __builtin_amdgcn_s_setprio(0);
        __syncthreads();
        cur ^= 1;
    }
#undef FSTAGE

    long m0 = mbase + wm * 64 + lg * 4;
#pragma unroll
    for (int mf = 0; mf < 4; mf++) {
        long mrow = m0 + mf * 16;
#pragma unroll
        for (int nf = 0; nf < 4; nf++) {
            int col = ncol0 + wn * 64 + nf * 16 + lr;
#pragma unroll
            for (int r = 0; r < 4; r++) out[(mrow + r) * 256 + col] = acc[mf][nf][r];
        }
    }
}

// ---------------- attention (32x32 MFMA, frag-major LDS) — round-10 form ------
// Best measured: ~197us attn, 0 bank conflicts. All structural variants measured
// null/negative (T15, q64/wave, dual QK chains, V-in-regs) — kept frozen.
// 1D grid 1280, block 256 (4 waves), q=32/wave, 2 waves/SIMD (256 regs exactly).
// XCD-chunked: logical = (lb&7)*160 + (lb>>3); -> bx(8) | by(16) | h.
// chunk g attends KV chunk (g+1)%4.  V == K.  Q pre-scaled by log2e -> p = exp2(S).

__global__ __launch_bounds__(256, 2) void attn_kernel(const unsigned short* __restrict__ Qb,
                                                      const unsigned short* __restrict__ KQg,
                                                      long headStrideQK,
                                                      const unsigned short* __restrict__ KTg,
                                                      long headStrideKT,
                                                      unsigned short* __restrict__ Ob,
                                                      long ldo, long colStride,
                                                      int chunkPerXcd) {
    const int lb = blockIdx.x;
    const int logical = (lb & 7) * chunkPerXcd + (lb >> 3);
    const int bx = logical & 7;
    const int by = (logical >> 3) & 15;
    const int h = logical >> 7;

    const unsigned short* Q = Qb + (long)h * colStride;  // Q row-major per-head
    const unsigned short* KQ = KQg + (long)h * headStrideQK;
    const unsigned short* KT = KTg + (long)h * headStrideKT;
    unsigned short* O = Ob + (long)h * colStride;
    const int b = by >> 2, g = by & 3;
    const long qrow0 = (long)b * SEQ + (long)g * CHK + (long)bx * 128;
    const int bgk = b * NG + ((g + 1) & 3);
    const unsigned short* KQc = KQ + (long)bgk * (256 * 1024);
    const unsigned short* KTc = KT + (long)bgk * (256 * 1024);

    __shared__ unsigned short Klds[2][8192];  // 2 x 16KB, frag-major
    __shared__ unsigned short Vlds[2][8192];  // 2 x 16KB, frag-major

    const int t = threadIdx.x;
    const int w = t >> 6, l = t & 63, l31 = l & 31, hi = l >> 5;

    // Q fragments (B-operand, 32x32x16): lane holds Q[q = l31][d = s*16 + hi*8 + j]
    s16x8 qf[16];
    {
        const unsigned short* qp = Q + (qrow0 + w * 32 + l31) * 256 + hi * 8;
#pragma unroll
        for (int s = 0; s < 16; s++) qf[s] = *(const s16x8*)(qp + s * 16);
    }

    f32x16 o[8];
#pragma unroll
    for (int i = 0; i < 8; i++)
#pragma unroll
        for (int j = 0; j < 16; j++) o[i][j] = 0.f;
    float l_part = 0.f;

#define STAGE(buf, kt_) do {                                                    \
        const unsigned short* Ks = KQc + (long)(kt_) * 8192 + l * 8;            \
        const unsigned short* Vs = KTc + (long)(kt_) * 8192 + l * 8;            \
        _Pragma("unroll")                                                       \
        for (int i = 0; i < 4; i++) {                                           \
            int c = w * 4 + i;                                                  \
            gload_lds16(Ks + c * 512, &Klds[buf][c * 512]);                     \
            gload_lds16(Vs + c * 512, &Vlds[buf][c * 512]);                     \
        }                                                                       \
    } while (0)

    STAGE(0, 0);
    __syncthreads();
    int cur = 0;

    for (int kt = 0; kt < 32; ++kt) {
        if (kt < 31) STAGE(cur ^ 1, kt + 1);   // prefetch next tile under compute

        // S = K_tile @ Q^T  (32x32 keys x q), lane col q = l31
        f32x16 st;
#pragma unroll
        for (int j = 0; j < 16; j++) st[j] = 0.f;
        __builtin_amdgcn_s_setprio(1);
#pragma unroll
        for (int ks = 0; ks < 16; ks++) {
            s16x8 kf = *(const s16x8*)(&Klds[cur][ks * 512 + l * 8]);
            st = __builtin_amdgcn_mfma_f32_32x32x16_bf16(kf, qf[ks], st, 0, 0, 0);
        }
        __builtin_amdgcn_s_setprio(0);

        // p = exp2(S) (Q pre-scaled); pack to bf16 pairs; sum into l_part
        u32 c0, c1, c2, c3, c4, c5, c6, c7;
        {
            float pa0 = __builtin_amdgcn_exp2f(st[0]),  pa1 = __builtin_amdgcn_exp2f(st[1]);
            float pa2 = __builtin_amdgcn_exp2f(st[2]),  pa3 = __builtin_amdgcn_exp2f(st[3]);
            float pa4 = __builtin_amdgcn_exp2f(st[4]),  pa5 = __builtin_amdgcn_exp2f(st[5]);
            float pa6 = __builtin_amdgcn_exp2f(st[6]),  pa7 = __builtin_amdgcn_exp2f(st[7]);
            float pa8 = __builtin_amdgcn_exp2f(st[8]),  pa9 = __builtin_amdgcn_exp2f(st[9]);
            float paA = __builtin_amdgcn_exp2f(st[10]), paB = __builtin_amdgcn_exp2f(st[11]);
            float paC = __builtin_amdgcn_exp2f(st[12]), paD = __builtin_amdgcn_exp2f(st[13]);
            float paE = __builtin_amdgcn_exp2f(st[14]), paF = __builtin_amdgcn_exp2f(st[15]);
            l_part += (((pa0 + pa1) + (pa2 + pa3)) + ((pa4 + pa5) + (pa6 + pa7)))
                    + (((pa8 + pa9) + (paA + paB)) + ((paC + paD) + (paE + paF)));
            c0 = cvtpk_bf16(pa0, pa1); c1 = cvtpk_bf16(pa2, pa3);
            c2 = cvtpk_bf16(pa4, pa5); c3 = cvtpk_bf16(pa6, pa7);
            c4 = cvtpk_bf16(pa8, pa9); c5 = cvtpk_bf16(paA, paB);
            c6 = cvtpk_bf16(paC, paD); c7 = cvtpk_bf16(paE, paF);
        }
        // redistribute: after swap, c0..c3 = PA frag (keys 0-15), c4..c7 = keys 16-31
        asm("v_permlane32_swap_b32 %0, %1" : "+v"(c0), "+v"(c2));
        asm("v_permlane32_swap_b32 %0, %1" : "+v"(c1), "+v"(c3));
        asm("v_permlane32_swap_b32 %0, %1" : "+v"(c4), "+v"(c6));
        asm("v_permlane32_swap_b32 %0, %1" : "+v"(c5), "+v"(c7));
        struct { u32 a, b, c, d; } x0 = {c0, c1, c2, c3};
        struct { u32 a, b, c, d; } x1 = {c4, c5, c6, c7};
        s16x8 pa0f = __builtin_bit_cast(s16x8, x0);
        s16x8 pa1f = __builtin_bit_cast(s16x8, x1);

        // O += P @ V   (V from frag-major LDS; contiguous conflict-free reads)
        __builtin_amdgcn_s_setprio(1);
#pragma unroll
        for (int ks = 0; ks < 2; ks++) {
            s16x8 paf = ks ? pa1f : pa0f;
#pragma unroll
            for (int nt = 0; nt < 8; nt++) {
                s16x8 bv = *(const s16x8*)(&Vlds[cur][(nt * 2 + ks) * 512 + l * 8]);
                o[nt] = __builtin_amdgcn_mfma_f32_32x32x16_bf16(paf, bv, o[nt], 0, 0, 0);
            }
        }
        __builtin_amdgcn_s_setprio(0);

        __syncthreads();   // drains vmcnt(0): next tile staged; cur reusable
        cur ^= 1;
    }
#undef STAGE

    // epilogue: lane owns l_part for q = l31 (its 16 keys) + partner half
    float lt = l_part + __shfl_xor(l_part, 32);
    float rinv = 1.0f / lt;
    float ri[16];
#pragma unroll
    for (int reg = 0; reg < 16; reg++) {
        int qr = (reg & 3) + 8 * (reg >> 2) + 4 * hi;
        ri[reg] = __shfl(rinv, qr);
    }
#pragma unroll
    for (int nt = 0; nt < 8; nt++) {
#pragma unroll
        for (int reg = 0; reg < 16; reg++) {
            int qr = (reg & 3) + 8 * (reg >> 2) + 4 * hi;
            O[(qrow0 + w * 32 + qr) * ldo + nt * 32 + l31] = f2bf(o[nt][reg] * ri[reg]);
        }
    }
}

// ---------------- host ----------------

extern "C" void kernel_launch(void* const* d_in, const int* in_sizes, int n_in,
                              void* d_out, int out_size, void* d_ws, size_t ws_size,
                              hipStream_t stream) {
    const float* x  = (const float*)d_in[0];
    const float* Wq = (const float*)d_in[1];
    const float* Wk = (const float*)d_in[2];
    const float* Wo = (const float*)d_in[3];
    float* out = (float*)d_out;
    char* ws = (char*)d_ws;

    unsigned short* xb  = (unsigned short*)(ws);
    unsigned short* wqt = (unsigned short*)(ws + 8388608);
    unsigned short* wkt = (unsigned short*)(ws + 9699328);
    unsigned short* wob = (unsigned short*)(ws + 11010048);
    char* dyn = ws + 12320768;

    prep<<<6016, 256, 0, stream>>>(x, Wq, Wk, Wo, xb, wqt, wkt, wob);

    const long perHeadElems = (long)BS_TOT * DIM;                // 4,194,304 (8MB bf16)
    const size_t FULL_NEED = 12320768ULL + 3ULL * 83886080ULL;   // ~264 MB (proven fits)

    if (ws_size >= FULL_NEED) {
        unsigned short* Qb  = (unsigned short*)dyn;              // also O (aliased)
        unsigned short* KQb = Qb + (long)NH * perHeadElems;
        unsigned short* KTb = KQb + (long)NH * perHeadElems;
        projQK<<<2560, 256, 0, stream>>>(xb, wqt, wkt, Qb, KQb, KTb,
                                         perHeadElems, perHeadElems);
        attn_kernel<<<1280, 256, 0, stream>>>(Qb, KQb, perHeadElems, KTb, perHeadElems,
                                              Qb, 256, perHeadElems, 160);
        final128<<<256, 256, 0, stream>>>(Qb, perHeadElems, wob, out);
    } else {
        unsigned short* Qh  = (unsigned short*)dyn;              // also O (aliased)
        unsigned short* KQh = Qh + perHeadElems;
        unsigned short* KTh = KQh + perHeadElems;
        hipMemsetAsync(d_out, 0, (size_t)out_size * 4, stream);
        for (int h = 0; h < NH; ++h) {
            proj_kernel<<<dim3(256, 1, 2), 256, 0, stream>>>(xb, wqt, wkt, Qh, KQh, KTh, h, 0, 0);
            attn_kernel<<<128, 256, 0, stream>>>(Qh, KQh, 0, KTh, 0, Qh, 256, 0, 16);
            final_kernel<<<256, 256, 0, stream>>>(Qh, 256, wob + h * 256, HD, out, 256, 1);
        }
    }
}